// Round 1
// baseline (1477.867 us; speedup 1.0000x reference)
//
#include <hip/hip_runtime.h>
#include <math.h>

#define N_NODES 100000
#define NFEAT 512
#define NHID 256
#define NCLASS 40

// ---------------- CSR build ----------------

__global__ void k_zero_i32(int* __restrict__ p, int n) {
    int i = blockIdx.x * blockDim.x + threadIdx.x;
    if (i < n) p[i] = 0;
}

__global__ void k_hist(const int* __restrict__ dst, int* __restrict__ deg, int E) {
    int i = blockIdx.x * blockDim.x + threadIdx.x;
    int stride = gridDim.x * blockDim.x;
    for (; i < E; i += stride) atomicAdd(&deg[dst[i]], 1);
}

// per-block inclusive scan of deg -> rowptr[idx+1]; block sums out
__global__ void k_scan1(const int* __restrict__ deg, int* __restrict__ rowptr,
                        int* __restrict__ bsum, int n) {
    __shared__ int sm[256];
    int t = threadIdx.x;
    int idx = blockIdx.x * 256 + t;
    int v = (idx < n) ? deg[idx] : 0;
    sm[t] = v;
    __syncthreads();
    for (int off = 1; off < 256; off <<= 1) {
        int a = (t >= off) ? sm[t - off] : 0;
        __syncthreads();
        sm[t] += a;
        __syncthreads();
    }
    if (idx < n) rowptr[idx + 1] = sm[t];
    if (t == 255) bsum[blockIdx.x] = sm[255];
    if (idx == 0) rowptr[0] = 0;
}

// single-block exclusive scan of block sums (nb <= 512)
__global__ void k_scan2(const int* __restrict__ bsum, int* __restrict__ boff, int nb) {
    __shared__ int sm[512];
    int t = threadIdx.x;
    int v = (t < nb) ? bsum[t] : 0;
    sm[t] = v;
    __syncthreads();
    for (int off = 1; off < 512; off <<= 1) {
        int a = (t >= off) ? sm[t - off] : 0;
        __syncthreads();
        sm[t] += a;
        __syncthreads();
    }
    if (t < nb) boff[t] = sm[t] - v;  // exclusive
}

// add block offsets; also init cursor = final rowptr[i]
__global__ void k_scan3(int* __restrict__ rowptr, const int* __restrict__ boff,
                        int* __restrict__ cursor, int n) {
    int idx = blockIdx.x * blockDim.x + threadIdx.x;
    if (idx < n) {
        int f = rowptr[idx + 1] + boff[idx >> 8];
        rowptr[idx + 1] = f;
        if (idx + 1 < n) cursor[idx + 1] = f;
        if (idx == 0) cursor[0] = 0;
    }
}

__global__ void k_fill(const int* __restrict__ src, const int* __restrict__ dst,
                       const float* __restrict__ ew, int* __restrict__ cursor,
                       int* __restrict__ csrc, float* __restrict__ cw, int E) {
    int i = blockIdx.x * blockDim.x + threadIdx.x;
    int stride = gridDim.x * blockDim.x;
    for (; i < E; i += stride) {
        int d = dst[i];
        int p = atomicAdd(&cursor[d], 1);
        csrc[p] = src[i];
        cw[p] = ew[i];
    }
}

// ---------------- GEMM1: sup1[100000,256] = x[100000,512] @ W1[512,256] ----------------
// block = 256 threads, tile M=32, N=256 (full), K-tiles of 32.
__global__ __launch_bounds__(256) void k_gemm1(const float* __restrict__ x,
                                               const float* __restrict__ W1,
                                               float* __restrict__ sup1) {
    __shared__ float As[32][32];     // 4 KB
    __shared__ float Bs[32 * 256];   // 32 KB
    int t = threadIdx.x;
    int m0 = blockIdx.x * 32;
    int tc = t & 63;        // col group: cols [tc*4, tc*4+4)
    int tr = t >> 6;        // row group: rows tr + 4*j, j=0..7
    int ar = t >> 3;        // A stage row
    int ac = (t & 7) * 4;   // A stage col (float4)

    float acc[8][4];
#pragma unroll
    for (int j = 0; j < 8; ++j)
#pragma unroll
        for (int i = 0; i < 4; ++i) acc[j][i] = 0.f;

    for (int k0 = 0; k0 < NFEAT; k0 += 32) {
        float4 av = *(const float4*)(x + (size_t)(m0 + ar) * NFEAT + k0 + ac);
        *(float4*)&As[ar][ac] = av;
#pragma unroll
        for (int i = 0; i < 8; ++i) {
            int f4 = t + 256 * i;  // 0..2047
            float4 bv = *(const float4*)(W1 + (size_t)k0 * NHID + (size_t)f4 * 4);
            *(float4*)(Bs + (size_t)f4 * 4) = bv;
        }
        __syncthreads();
#pragma unroll
        for (int kk = 0; kk < 32; ++kk) {
            float4 b = *(float4*)(Bs + kk * 256 + tc * 4);
#pragma unroll
            for (int j = 0; j < 8; ++j) {
                float a = As[tr + 4 * j][kk];
                acc[j][0] += a * b.x;
                acc[j][1] += a * b.y;
                acc[j][2] += a * b.z;
                acc[j][3] += a * b.w;
            }
        }
        __syncthreads();
    }
#pragma unroll
    for (int j = 0; j < 8; ++j) {
        float4 v = make_float4(acc[j][0], acc[j][1], acc[j][2], acc[j][3]);
        *(float4*)(sup1 + (size_t)(m0 + tr + 4 * j) * NHID + tc * 4) = v;
    }
}

// ---------------- propagate 1: h1[i,:] = sum_e w_e * sup1[src_e,:] (256 feats) ----------------
// one wave per node; lane handles float4 (lane*4 .. lane*4+3) => full 256-f32 row
__global__ __launch_bounds__(256) void k_prop1(const float* __restrict__ sup1,
                                               const int* __restrict__ rowptr,
                                               const int* __restrict__ csrc,
                                               const float* __restrict__ cw,
                                               float* __restrict__ h1) {
    int gid = blockIdx.x * blockDim.x + threadIdx.x;
    int wid = gid >> 6;
    int lane = gid & 63;
    if (wid >= N_NODES) return;
    int beg = rowptr[wid], end = rowptr[wid + 1];
    float4 acc = make_float4(0.f, 0.f, 0.f, 0.f);
    int e = beg;
    for (; e + 1 < end; e += 2) {
        int s0 = csrc[e];
        float w0 = cw[e];
        int s1 = csrc[e + 1];
        float w1 = cw[e + 1];
        float4 r0 = *(const float4*)(sup1 + (size_t)s0 * NHID + lane * 4);
        float4 r1 = *(const float4*)(sup1 + (size_t)s1 * NHID + lane * 4);
        acc.x += w0 * r0.x + w1 * r1.x;
        acc.y += w0 * r0.y + w1 * r1.y;
        acc.z += w0 * r0.z + w1 * r1.z;
        acc.w += w0 * r0.w + w1 * r1.w;
    }
    if (e < end) {
        int s0 = csrc[e];
        float w0 = cw[e];
        float4 r0 = *(const float4*)(sup1 + (size_t)s0 * NHID + lane * 4);
        acc.x += w0 * r0.x;
        acc.y += w0 * r0.y;
        acc.z += w0 * r0.z;
        acc.w += w0 * r0.w;
    }
    *(float4*)(h1 + (size_t)wid * NHID + lane * 4) = acc;
}

// ---------------- GEMM2 fused: sup2[100000,40] = relu(h1 + b1) @ W2[256,40] ----------------
__global__ __launch_bounds__(256) void k_gemm2(const float* __restrict__ h1,
                                               const float* __restrict__ W2,
                                               const float* __restrict__ b1,
                                               float* __restrict__ sup2) {
    __shared__ float w2s[NHID * NCLASS];  // 40 KB
    __shared__ float b1s[NHID];
    __shared__ float rows[4][NHID];  // per-wave row buffer
    int t = threadIdx.x;
    for (int i = t; i < NHID * NCLASS; i += 256) w2s[i] = W2[i];
    b1s[t] = b1[t];
    __syncthreads();
    int wave = t >> 6, lane = t & 63;
    int gw = blockIdx.x * 4 + wave;
    int nw = gridDim.x * 4;
    for (int r = gw; r < N_NODES; r += nw) {
        const float* hr = h1 + (size_t)r * NHID;
        float4 v = *(const float4*)(hr + lane * 4);
        v.x = fmaxf(v.x + b1s[lane * 4 + 0], 0.f);
        v.y = fmaxf(v.y + b1s[lane * 4 + 1], 0.f);
        v.z = fmaxf(v.z + b1s[lane * 4 + 2], 0.f);
        v.w = fmaxf(v.w + b1s[lane * 4 + 3], 0.f);
        *(float4*)&rows[wave][lane * 4] = v;
        // wave-private LDS buffer: same-wave ds ops are ordered; no barrier needed
        if (lane < NCLASS) {
            float acc = 0.f;
#pragma unroll 8
            for (int k = 0; k < NHID; ++k) acc += rows[wave][k] * w2s[k * NCLASS + lane];
            sup2[(size_t)r * NCLASS + lane] = acc;
        }
    }
}

// ---------------- propagate 2 + b2 + log_softmax ----------------
__global__ __launch_bounds__(256) void k_prop2(const float* __restrict__ sup2,
                                               const int* __restrict__ rowptr,
                                               const int* __restrict__ csrc,
                                               const float* __restrict__ cw,
                                               const float* __restrict__ b2,
                                               float* __restrict__ out) {
    int gid = blockIdx.x * blockDim.x + threadIdx.x;
    int wid = gid >> 6;
    int lane = gid & 63;
    if (wid >= N_NODES) return;
    int beg = rowptr[wid], end = rowptr[wid + 1];
    float acc = 0.f;
    int e = beg;
    for (; e + 1 < end; e += 2) {
        int s0 = csrc[e];
        float w0 = cw[e];
        int s1 = csrc[e + 1];
        float w1 = cw[e + 1];
        if (lane < NCLASS)
            acc += w0 * sup2[(size_t)s0 * NCLASS + lane] + w1 * sup2[(size_t)s1 * NCLASS + lane];
    }
    if (e < end) {
        int s0 = csrc[e];
        float w0 = cw[e];
        if (lane < NCLASS) acc += w0 * sup2[(size_t)s0 * NCLASS + lane];
    }
    float v = (lane < NCLASS) ? (acc + b2[lane]) : -INFINITY;
    // max over 64 lanes
    float m = v;
#pragma unroll
    for (int off = 32; off >= 1; off >>= 1) m = fmaxf(m, __shfl_xor(m, off));
    float ex = (lane < NCLASS) ? expf(v - m) : 0.f;
    float s = ex;
#pragma unroll
    for (int off = 32; off >= 1; off >>= 1) s += __shfl_xor(s, off);
    if (lane < NCLASS) out[(size_t)wid * NCLASS + lane] = v - m - logf(s);
}

// ---------------- launch ----------------

extern "C" void kernel_launch(void* const* d_in, const int* in_sizes, int n_in,
                              void* d_out, int out_size, void* d_ws, size_t ws_size,
                              hipStream_t stream) {
    const float* x = (const float*)d_in[0];
    const int* ei = (const int*)d_in[1];
    const float* ew = (const float*)d_in[2];
    const float* W1 = (const float*)d_in[3];
    const float* b1 = (const float*)d_in[4];
    const float* W2 = (const float*)d_in[5];
    const float* b2 = (const float*)d_in[6];
    float* out = (float*)d_out;

    int E = in_sizes[1] / 2;
    const int* src = ei;
    const int* dst = ei + E;

    char* w = (char*)d_ws;
    size_t off = 0;
    auto alloc = [&](size_t bytes) {
        void* p = w + off;
        off += (bytes + 255) & ~(size_t)255;
        return p;
    };
    float* sup1 = (float*)alloc((size_t)N_NODES * NHID * 4);   // 102.4 MB
    float* h1 = (float*)alloc((size_t)N_NODES * NHID * 4);     // 102.4 MB
    int* csrc = (int*)alloc((size_t)E * 4);
    float* cw = (float*)alloc((size_t)E * 4);
    int* rowptr = (int*)alloc((size_t)(N_NODES + 1) * 4);
    int* cursor = (int*)alloc((size_t)N_NODES * 4);
    int* deg = (int*)alloc((size_t)N_NODES * 4);
    int* bsum = (int*)alloc(2048);
    int* boff = (int*)alloc(2048);
    float* sup2 = sup1;  // alias: sup1 dead after prop1

    const int NB = (N_NODES + 255) / 256;  // 391

    k_zero_i32<<<NB, 256, 0, stream>>>(deg, N_NODES);
    k_hist<<<2048, 256, 0, stream>>>(dst, deg, E);
    k_scan1<<<NB, 256, 0, stream>>>(deg, rowptr, bsum, N_NODES);
    k_scan2<<<1, 512, 0, stream>>>(bsum, boff, NB);
    k_scan3<<<NB, 256, 0, stream>>>(rowptr, boff, cursor, N_NODES);
    k_fill<<<2048, 256, 0, stream>>>(src, dst, ew, cursor, csrc, cw, E);

    k_gemm1<<<N_NODES / 32, 256, 0, stream>>>(x, W1, sup1);
    k_prop1<<<(N_NODES + 3) / 4, 256, 0, stream>>>(sup1, rowptr, csrc, cw, h1);
    k_gemm2<<<2048, 256, 0, stream>>>(h1, W2, b1, sup2);
    k_prop2<<<(N_NODES + 3) / 4, 256, 0, stream>>>(sup2, rowptr, csrc, cw, b2, out);
}

// Round 2
// 1009.228 us; speedup vs baseline: 1.4644x; 1.4644x over previous
//
#include <hip/hip_runtime.h>
#include <math.h>

#define N_NODES 100000
#define M_PAD 100096  /* 782*128 */
#define NFEAT 512
#define NHID 256
#define NCLASS 40

typedef __attribute__((ext_vector_type(8))) short bf16x8;
typedef __attribute__((ext_vector_type(4))) float f32x4;

__device__ __forceinline__ unsigned short f2bf(float f) {
    unsigned int u = __builtin_bit_cast(unsigned int, f);
    u += 0x7fffu + ((u >> 16) & 1u);  // RNE
    return (unsigned short)(u >> 16);
}
__device__ __forceinline__ void bf2x2(unsigned int u, float& f0, float& f1) {
    f0 = __builtin_bit_cast(float, u << 16);
    f1 = __builtin_bit_cast(float, u & 0xffff0000u);
}
__device__ __forceinline__ void gload16(const void* g, void* l) {
    __builtin_amdgcn_global_load_lds(
        (const __attribute__((address_space(1))) unsigned int*)g,
        (__attribute__((address_space(3))) unsigned int*)l, 16, 0, 0);
}

// ---------------- CSR build ----------------

__global__ void k_zero_i32(int* __restrict__ p, int n) {
    int i = blockIdx.x * blockDim.x + threadIdx.x;
    if (i < n) p[i] = 0;
}

__global__ void k_hist(const int* __restrict__ dst, int* __restrict__ deg, int E) {
    int i = blockIdx.x * blockDim.x + threadIdx.x;
    int stride = gridDim.x * blockDim.x;
    for (; i < E; i += stride) atomicAdd(&deg[dst[i]], 1);
}

__global__ void k_scan1(const int* __restrict__ deg, int* __restrict__ rowptr,
                        int* __restrict__ bsum, int n) {
    __shared__ int sm[256];
    int t = threadIdx.x;
    int idx = blockIdx.x * 256 + t;
    int v = (idx < n) ? deg[idx] : 0;
    sm[t] = v;
    __syncthreads();
    for (int off = 1; off < 256; off <<= 1) {
        int a = (t >= off) ? sm[t - off] : 0;
        __syncthreads();
        sm[t] += a;
        __syncthreads();
    }
    if (idx < n) rowptr[idx + 1] = sm[t];
    if (t == 255) bsum[blockIdx.x] = sm[255];
    if (idx == 0) rowptr[0] = 0;
}

__global__ void k_scan2(const int* __restrict__ bsum, int* __restrict__ boff, int nb) {
    __shared__ int sm[512];
    int t = threadIdx.x;
    int v = (t < nb) ? bsum[t] : 0;
    sm[t] = v;
    __syncthreads();
    for (int off = 1; off < 512; off <<= 1) {
        int a = (t >= off) ? sm[t - off] : 0;
        __syncthreads();
        sm[t] += a;
        __syncthreads();
    }
    if (t < nb) boff[t] = sm[t] - v;
}

__global__ void k_scan3(int* __restrict__ rowptr, const int* __restrict__ boff,
                        int* __restrict__ cursor, int n) {
    int idx = blockIdx.x * blockDim.x + threadIdx.x;
    if (idx < n) {
        int f = rowptr[idx + 1] + boff[idx >> 8];
        rowptr[idx + 1] = f;
        if (idx + 1 < n) cursor[idx + 1] = f;
        if (idx == 0) cursor[0] = 0;
    }
}

__global__ void k_fill(const int* __restrict__ src, const int* __restrict__ dst,
                       const float* __restrict__ ew, int* __restrict__ cursor,
                       int* __restrict__ csrc, float* __restrict__ cw, int E) {
    int i = blockIdx.x * blockDim.x + threadIdx.x;
    int stride = gridDim.x * blockDim.x;
    for (; i < E; i += stride) {
        int d = dst[i];
        int p = atomicAdd(&cursor[d], 1);
        csrc[p] = src[i];
        cw[p] = ew[i];
    }
}

// ---------------- converts ----------------

// x f32 [100000][512] -> xb bf16 [M_PAD][512], pad rows zero. 8 elems/thread.
__global__ __launch_bounds__(256) void k_cvt_x(const float* __restrict__ x,
                                               unsigned short* __restrict__ xb) {
    size_t i = ((size_t)blockIdx.x * 256 + threadIdx.x) * 8;
    const size_t real = (size_t)N_NODES * NFEAT;   // divisible by 8
    const size_t total = (size_t)M_PAD * NFEAT;
    if (i >= total) return;
    unsigned short o[8];
    if (i < real) {
        float4 v0 = *(const float4*)(x + i);
        float4 v1 = *(const float4*)(x + i + 4);
        o[0]=f2bf(v0.x); o[1]=f2bf(v0.y); o[2]=f2bf(v0.z); o[3]=f2bf(v0.w);
        o[4]=f2bf(v1.x); o[5]=f2bf(v1.y); o[6]=f2bf(v1.z); o[7]=f2bf(v1.w);
    } else {
        for (int j = 0; j < 8; ++j) o[j] = 0;
    }
    *(uint4*)(xb + i) = *(const uint4*)o;
}

// W1 f32 [512][256] -> w1t bf16 [256][512] (transposed)
__global__ __launch_bounds__(256) void k_cvt_w1(const float* __restrict__ W1,
                                                unsigned short* __restrict__ w1t) {
    int idx = blockIdx.x * 256 + threadIdx.x;
    if (idx >= NHID * NFEAT) return;
    int n = idx >> 9, k = idx & 511;
    w1t[idx] = f2bf(W1[(size_t)k * NHID + n]);
}

// ---------------- GEMM1 (MFMA bf16): sup1 = xb @ W1 ----------------
// 128x128 tile, BK=64, 256 thr (4 waves 2x2), double-buffered global_load_lds,
// XOR swizzle byte^=((row&7)<<4) applied on the SOURCE address (linear LDS dest)
// and on the ds_read address.
__global__ __launch_bounds__(256) void k_gemm1(const unsigned short* __restrict__ xb,
                                               const unsigned short* __restrict__ w1t,
                                               unsigned short* __restrict__ sup1) {
    __shared__ char smem[65536];  // A: 2x16KB @0, B: 2x16KB @32768
    const int t = threadIdx.x;
    const int w = t >> 6, lane = t & 63;
    const int m0 = blockIdx.x * 128;
    const int n0 = blockIdx.y * 128;
    const int wm = w >> 1, wn = w & 1;
    const int r15 = lane & 15, hi = lane >> 4;

    f32x4 acc[4][4];
#pragma unroll
    for (int i = 0; i < 4; ++i)
#pragma unroll
        for (int j = 0; j < 4; ++j) acc[i][j] = (f32x4){0.f, 0.f, 0.f, 0.f};

    const char* xsrc = (const char*)xb;
    const char* wsrc = (const char*)w1t;

#define STAGE(kt, b)                                                                   \
    {                                                                                  \
        char* Ab = smem + (b) * 16384;                                                 \
        char* Bb = smem + 32768 + (b) * 16384;                                         \
        _Pragma("unroll") for (int i = 0; i < 4; ++i) {                                \
            int c = i * 256 + w * 64 + lane;                                           \
            int row = c >> 3;                                                          \
            int sb = ((c & 7) * 16) ^ ((row & 7) << 4);                                \
            gload16(xsrc + ((size_t)(m0 + row) * 1024 + (kt) * 128 + sb),              \
                    Ab + (size_t)(i * 256 + w * 64) * 16);                             \
            gload16(wsrc + ((size_t)(n0 + row) * 1024 + (kt) * 128 + sb),              \
                    Bb + (size_t)(i * 256 + w * 64) * 16);                             \
        }                                                                              \
    }

    STAGE(0, 0);
    for (int kt = 0; kt < 8; ++kt) {
        __syncthreads();  // drains vmcnt(0): buf (kt&1) ready
        if (kt < 7) STAGE(kt + 1, (kt + 1) & 1);
        const char* Ab = smem + (kt & 1) * 16384;
        const char* Bb = smem + 32768 + (kt & 1) * 16384;
#pragma unroll
        for (int ks = 0; ks < 2; ++ks) {
            bf16x8 a[4], bb[4];
#pragma unroll
            for (int i = 0; i < 4; ++i) {
                int r = wm * 64 + i * 16 + r15;
                int cb = (ks * 64 + hi * 16) ^ ((r & 7) << 4);
                a[i] = *(const bf16x8*)(Ab + r * 128 + cb);
            }
#pragma unroll
            for (int j = 0; j < 4; ++j) {
                int n = wn * 64 + j * 16 + r15;
                int cb = (ks * 64 + hi * 16) ^ ((n & 7) << 4);
                bb[j] = *(const bf16x8*)(Bb + n * 128 + cb);
            }
#pragma unroll
            for (int i = 0; i < 4; ++i)
#pragma unroll
                for (int j = 0; j < 4; ++j)
                    acc[i][j] = __builtin_amdgcn_mfma_f32_16x16x32_bf16(a[i], bb[j], acc[i][j], 0, 0, 0);
        }
    }
#undef STAGE

    // C/D layout: col = lane&15, row = (lane>>4)*4 + reg  [m89]
#pragma unroll
    for (int i = 0; i < 4; ++i) {
        int rowb = m0 + wm * 64 + i * 16 + hi * 4;
#pragma unroll
        for (int j = 0; j < 4; ++j) {
            int col = n0 + wn * 64 + j * 16 + r15;
#pragma unroll
            for (int r = 0; r < 4; ++r)
                sup1[(size_t)(rowb + r) * NHID + col] = f2bf(acc[i][j][r]);
        }
    }
}

// ---------------- propagate 1 (bf16 rows): h1[i,:] = sum_e w_e * sup1[src_e,:] ----------------
// one wave per node; lane covers 4 bf16 (8 B); 4-edge unroll
__global__ __launch_bounds__(256) void k_prop1(const unsigned short* __restrict__ sup1,
                                               const int* __restrict__ rowptr,
                                               const int* __restrict__ csrc,
                                               const float* __restrict__ cw,
                                               unsigned short* __restrict__ h1) {
    int gid = blockIdx.x * blockDim.x + threadIdx.x;
    int wid = gid >> 6;
    int lane = gid & 63;
    if (wid >= N_NODES) return;
    int beg = rowptr[wid], end = rowptr[wid + 1];
    float a0 = 0.f, a1 = 0.f, a2 = 0.f, a3 = 0.f;
    int e = beg;
    for (; e + 3 < end; e += 4) {
        int s0 = csrc[e], s1 = csrc[e + 1], s2 = csrc[e + 2], s3 = csrc[e + 3];
        float w0 = cw[e], w1 = cw[e + 1], w2 = cw[e + 2], w3 = cw[e + 3];
        uint2 r0 = *(const uint2*)(sup1 + (size_t)s0 * NHID + lane * 4);
        uint2 r1 = *(const uint2*)(sup1 + (size_t)s1 * NHID + lane * 4);
        uint2 r2 = *(const uint2*)(sup1 + (size_t)s2 * NHID + lane * 4);
        uint2 r3 = *(const uint2*)(sup1 + (size_t)s3 * NHID + lane * 4);
        float f0, f1, f2, f3;
        bf2x2(r0.x, f0, f1); bf2x2(r0.y, f2, f3);
        a0 += w0 * f0; a1 += w0 * f1; a2 += w0 * f2; a3 += w0 * f3;
        bf2x2(r1.x, f0, f1); bf2x2(r1.y, f2, f3);
        a0 += w1 * f0; a1 += w1 * f1; a2 += w1 * f2; a3 += w1 * f3;
        bf2x2(r2.x, f0, f1); bf2x2(r2.y, f2, f3);
        a0 += w2 * f0; a1 += w2 * f1; a2 += w2 * f2; a3 += w2 * f3;
        bf2x2(r3.x, f0, f1); bf2x2(r3.y, f2, f3);
        a0 += w3 * f0; a1 += w3 * f1; a2 += w3 * f2; a3 += w3 * f3;
    }
    for (; e < end; ++e) {
        int s0 = csrc[e];
        float w0 = cw[e];
        uint2 r0 = *(const uint2*)(sup1 + (size_t)s0 * NHID + lane * 4);
        float f0, f1, f2, f3;
        bf2x2(r0.x, f0, f1); bf2x2(r0.y, f2, f3);
        a0 += w0 * f0; a1 += w0 * f1; a2 += w0 * f2; a3 += w0 * f3;
    }
    unsigned short o[4] = {f2bf(a0), f2bf(a1), f2bf(a2), f2bf(a3)};
    *(uint2*)(h1 + (size_t)wid * NHID + lane * 4) = *(const uint2*)o;
}

// ---------------- GEMM2 fused: sup2 = relu(h1 + b1) @ W2 ----------------
__global__ __launch_bounds__(256) void k_gemm2(const unsigned short* __restrict__ h1,
                                               const float* __restrict__ W2,
                                               const float* __restrict__ b1,
                                               float* __restrict__ sup2) {
    __shared__ float w2s[NHID * NCLASS];  // 40 KB
    __shared__ float b1s[NHID];
    __shared__ float rows[4][NHID];
    int t = threadIdx.x;
    for (int i = t; i < NHID * NCLASS; i += 256) w2s[i] = W2[i];
    b1s[t] = b1[t];
    __syncthreads();
    int wave = t >> 6, lane = t & 63;
    int gw = blockIdx.x * 4 + wave;
    int nw = gridDim.x * 4;
    for (int r = gw; r < N_NODES; r += nw) {
        uint2 v = *(const uint2*)(h1 + (size_t)r * NHID + lane * 4);
        float x0, x1, x2, x3;
        bf2x2(v.x, x0, x1); bf2x2(v.y, x2, x3);
        x0 = fmaxf(x0 + b1s[lane * 4 + 0], 0.f);
        x1 = fmaxf(x1 + b1s[lane * 4 + 1], 0.f);
        x2 = fmaxf(x2 + b1s[lane * 4 + 2], 0.f);
        x3 = fmaxf(x3 + b1s[lane * 4 + 3], 0.f);
        rows[wave][lane * 4 + 0] = x0;
        rows[wave][lane * 4 + 1] = x1;
        rows[wave][lane * 4 + 2] = x2;
        rows[wave][lane * 4 + 3] = x3;
        // wave-private LDS buffer: same-wave ds ops are ordered; no barrier needed
        if (lane < NCLASS) {
            float acc = 0.f;
#pragma unroll 8
            for (int k = 0; k < NHID; ++k) acc += rows[wave][k] * w2s[k * NCLASS + lane];
            sup2[(size_t)r * NCLASS + lane] = acc;
        }
    }
}

// ---------------- propagate 2 + b2 + log_softmax ----------------
__global__ __launch_bounds__(256) void k_prop2(const float* __restrict__ sup2,
                                               const int* __restrict__ rowptr,
                                               const int* __restrict__ csrc,
                                               const float* __restrict__ cw,
                                               const float* __restrict__ b2,
                                               float* __restrict__ out) {
    int gid = blockIdx.x * blockDim.x + threadIdx.x;
    int wid = gid >> 6;
    int lane = gid & 63;
    if (wid >= N_NODES) return;
    int beg = rowptr[wid], end = rowptr[wid + 1];
    float acc = 0.f;
    int e = beg;
    for (; e + 1 < end; e += 2) {
        int s0 = csrc[e];
        float w0 = cw[e];
        int s1 = csrc[e + 1];
        float w1 = cw[e + 1];
        if (lane < NCLASS)
            acc += w0 * sup2[(size_t)s0 * NCLASS + lane] + w1 * sup2[(size_t)s1 * NCLASS + lane];
    }
    if (e < end) {
        int s0 = csrc[e];
        float w0 = cw[e];
        if (lane < NCLASS) acc += w0 * sup2[(size_t)s0 * NCLASS + lane];
    }
    float v = (lane < NCLASS) ? (acc + b2[lane]) : -INFINITY;
    float m = v;
#pragma unroll
    for (int off = 32; off >= 1; off >>= 1) m = fmaxf(m, __shfl_xor(m, off));
    float ex = (lane < NCLASS) ? expf(v - m) : 0.f;
    float s = ex;
#pragma unroll
    for (int off = 32; off >= 1; off >>= 1) s += __shfl_xor(s, off);
    if (lane < NCLASS) out[(size_t)wid * NCLASS + lane] = v - m - logf(s);
}

// ---------------- launch ----------------

extern "C" void kernel_launch(void* const* d_in, const int* in_sizes, int n_in,
                              void* d_out, int out_size, void* d_ws, size_t ws_size,
                              hipStream_t stream) {
    const float* x = (const float*)d_in[0];
    const int* ei = (const int*)d_in[1];
    const float* ew = (const float*)d_in[2];
    const float* W1 = (const float*)d_in[3];
    const float* b1 = (const float*)d_in[4];
    const float* W2 = (const float*)d_in[5];
    const float* b2 = (const float*)d_in[6];
    float* out = (float*)d_out;

    int E = in_sizes[1] / 2;
    const int* src = ei;
    const int* dst = ei + E;

    char* w = (char*)d_ws;
    size_t off = 0;
    auto alloc = [&](size_t bytes) {
        void* p = w + off;
        off += (bytes + 255) & ~(size_t)255;
        return p;
    };
    unsigned short* xb = (unsigned short*)alloc((size_t)M_PAD * NFEAT * 2);   // 102.5 MB
    unsigned short* w1t = (unsigned short*)alloc((size_t)NHID * NFEAT * 2);   // 256 KB
    unsigned short* sup1 = (unsigned short*)alloc((size_t)M_PAD * NHID * 2);  // 51.2 MB
    unsigned short* h1 = (unsigned short*)alloc((size_t)N_NODES * NHID * 2);  // 51.2 MB
    int* csrc = (int*)alloc((size_t)E * 4);
    float* cw = (float*)alloc((size_t)E * 4);
    int* rowptr = (int*)alloc((size_t)(N_NODES + 1) * 4);
    int* cursor = (int*)alloc((size_t)N_NODES * 4);
    int* deg = (int*)alloc((size_t)N_NODES * 4);
    int* bsum = (int*)alloc(2048);
    int* boff = (int*)alloc(2048);
    float* sup2 = (float*)xb;  // alias: xb dead after gemm1

    const int NB = (N_NODES + 255) / 256;  // 391

    k_cvt_x<<<(int)(((size_t)M_PAD * NFEAT / 8 + 255) / 256), 256, 0, stream>>>(x, xb);
    k_cvt_w1<<<(NHID * NFEAT + 255) / 256, 256, 0, stream>>>(W1, w1t);

    k_zero_i32<<<NB, 256, 0, stream>>>(deg, N_NODES);
    k_hist<<<2048, 256, 0, stream>>>(dst, deg, E);
    k_scan1<<<NB, 256, 0, stream>>>(deg, rowptr, bsum, N_NODES);
    k_scan2<<<1, 512, 0, stream>>>(bsum, boff, NB);
    k_scan3<<<NB, 256, 0, stream>>>(rowptr, boff, cursor, N_NODES);
    k_fill<<<2048, 256, 0, stream>>>(src, dst, ew, cursor, csrc, cw, E);

    dim3 g1(M_PAD / 128, NHID / 128);
    k_gemm1<<<g1, 256, 0, stream>>>(xb, w1t, sup1);
    k_prop1<<<(N_NODES + 3) / 4, 256, 0, stream>>>(sup1, rowptr, csrc, cw, h1);
    k_gemm2<<<2048, 256, 0, stream>>>(h1, W2, b1, sup2);
    k_prop2<<<(N_NODES + 3) / 4, 256, 0, stream>>>(sup2, rowptr, csrc, cw, b2, out);
}

// Round 3
// 999.357 us; speedup vs baseline: 1.4788x; 1.0099x over previous
//
#include <hip/hip_runtime.h>
#include <math.h>

#define N_NODES 100000
#define M_PAD 100096  /* 782*128 */
#define NFEAT 512
#define NHID 256
#define NCLASS 40

typedef __attribute__((ext_vector_type(8))) short bf16x8;
typedef __attribute__((ext_vector_type(4))) float f32x4;

__device__ __forceinline__ unsigned short f2bf(float f) {
    unsigned int u = __builtin_bit_cast(unsigned int, f);
    u += 0x7fffu + ((u >> 16) & 1u);  // RNE
    return (unsigned short)(u >> 16);
}
__device__ __forceinline__ float bf2f(unsigned short u) {
    return __builtin_bit_cast(float, (unsigned int)u << 16);
}
__device__ __forceinline__ void bf2x2(unsigned int u, float& f0, float& f1) {
    f0 = __builtin_bit_cast(float, u << 16);
    f1 = __builtin_bit_cast(float, u & 0xffff0000u);
}
__device__ __forceinline__ void gload16(const void* g, void* l) {
    __builtin_amdgcn_global_load_lds(
        (const __attribute__((address_space(1))) unsigned int*)g,
        (__attribute__((address_space(3))) unsigned int*)l, 16, 0, 0);
}

// ---------------- fused pre-pass: hist (blocks 0..2047) + cvt_x + cvt_w1 ----------------
#define HIST_BLOCKS 2048
#define CVTX_BLOCKS 25024 /* M_PAD*512/8/256 */
#define CVTW_BLOCKS 512   /* 256*512/256 */

__global__ __launch_bounds__(256) void k_pre(const int* __restrict__ dst, int* __restrict__ deg,
                                             int E, const float* __restrict__ x,
                                             unsigned short* __restrict__ xb,
                                             const float* __restrict__ W1,
                                             unsigned short* __restrict__ w1t) {
    int b = blockIdx.x;
    int t = threadIdx.x;
    if (b < HIST_BLOCKS) {
        // histogram of dst (deg pre-zeroed by memset); latency-bound, runs first
        int i = b * 256 + t;
        int stride = HIST_BLOCKS * 256;
        for (; i < E; i += stride) atomicAdd(&deg[dst[i]], 1);
    } else if (b < HIST_BLOCKS + CVTX_BLOCKS) {
        // x f32 -> xb bf16, pad rows zero; 8 elems/thread
        size_t i = ((size_t)(b - HIST_BLOCKS) * 256 + t) * 8;
        const size_t real = (size_t)N_NODES * NFEAT;
        unsigned short o[8];
        if (i < real) {
            float4 v0 = *(const float4*)(x + i);
            float4 v1 = *(const float4*)(x + i + 4);
            o[0]=f2bf(v0.x); o[1]=f2bf(v0.y); o[2]=f2bf(v0.z); o[3]=f2bf(v0.w);
            o[4]=f2bf(v1.x); o[5]=f2bf(v1.y); o[6]=f2bf(v1.z); o[7]=f2bf(v1.w);
        } else {
            for (int j = 0; j < 8; ++j) o[j] = 0;
        }
        *(uint4*)(xb + i) = *(const uint4*)o;
    } else {
        // W1 [512][256] -> w1t [256][512] transposed bf16
        int idx = (b - HIST_BLOCKS - CVTX_BLOCKS) * 256 + t;
        int n = idx >> 9, k = idx & 511;
        w1t[idx] = f2bf(W1[(size_t)k * NHID + n]);
    }
}

// ---------------- scans ----------------

__global__ void k_scan1(const int* __restrict__ deg, int* __restrict__ rowptr,
                        int* __restrict__ bsum, int n) {
    __shared__ int sm[256];
    int t = threadIdx.x;
    int idx = blockIdx.x * 256 + t;
    int v = (idx < n) ? deg[idx] : 0;
    sm[t] = v;
    __syncthreads();
    for (int off = 1; off < 256; off <<= 1) {
        int a = (t >= off) ? sm[t - off] : 0;
        __syncthreads();
        sm[t] += a;
        __syncthreads();
    }
    if (idx < n) rowptr[idx + 1] = sm[t];
    if (t == 255) bsum[blockIdx.x] = sm[255];
    if (idx == 0) rowptr[0] = 0;
}

__global__ void k_scan2(const int* __restrict__ bsum, int* __restrict__ boff, int nb) {
    __shared__ int sm[512];
    int t = threadIdx.x;
    int v = (t < nb) ? bsum[t] : 0;
    sm[t] = v;
    __syncthreads();
    for (int off = 1; off < 512; off <<= 1) {
        int a = (t >= off) ? sm[t - off] : 0;
        __syncthreads();
        sm[t] += a;
        __syncthreads();
    }
    if (t < nb) boff[t] = sm[t] - v;
}

__global__ void k_scan3(int* __restrict__ rowptr, const int* __restrict__ boff,
                        int* __restrict__ cursor, int n) {
    int idx = blockIdx.x * blockDim.x + threadIdx.x;
    if (idx < n) {
        int f = rowptr[idx + 1] + boff[idx >> 8];
        rowptr[idx + 1] = f;
        if (idx + 1 < n) cursor[idx + 1] = f;
        if (idx == 0) cursor[0] = 0;
    }
}

// ---------------- fill: packed (src, w) 8B scatter ----------------

__global__ void k_fill(const int* __restrict__ src, const int* __restrict__ dst,
                       const float* __restrict__ ew, int* __restrict__ cursor,
                       uint2* __restrict__ cedge, int E) {
    int i = blockIdx.x * blockDim.x + threadIdx.x;
    int stride = gridDim.x * blockDim.x;
    for (; i < E; i += stride) {
        int d = dst[i];
        int p = atomicAdd(&cursor[d], 1);
        cedge[p] = make_uint2((unsigned)src[i], __builtin_bit_cast(unsigned, ew[i]));
    }
}

// ---------------- GEMM1 (MFMA bf16): sup1 = xb @ W1 ----------------
__global__ __launch_bounds__(256) void k_gemm1(const unsigned short* __restrict__ xb,
                                               const unsigned short* __restrict__ w1t,
                                               unsigned short* __restrict__ sup1) {
    __shared__ char smem[65536];  // A: 2x16KB @0, B: 2x16KB @32768
    const int t = threadIdx.x;
    const int w = t >> 6, lane = t & 63;
    const int m0 = blockIdx.x * 128;
    const int n0 = blockIdx.y * 128;
    const int wm = w >> 1, wn = w & 1;
    const int r15 = lane & 15, hi = lane >> 4;

    f32x4 acc[4][4];
#pragma unroll
    for (int i = 0; i < 4; ++i)
#pragma unroll
        for (int j = 0; j < 4; ++j) acc[i][j] = (f32x4){0.f, 0.f, 0.f, 0.f};

    const char* xsrc = (const char*)xb;
    const char* wsrc = (const char*)w1t;

#define STAGE(kt, b)                                                                   \
    {                                                                                  \
        char* Ab = smem + (b) * 16384;                                                 \
        char* Bb = smem + 32768 + (b) * 16384;                                         \
        _Pragma("unroll") for (int i = 0; i < 4; ++i) {                                \
            int c = i * 256 + w * 64 + lane;                                           \
            int row = c >> 3;                                                          \
            int sb = ((c & 7) * 16) ^ ((row & 7) << 4);                                \
            gload16(xsrc + ((size_t)(m0 + row) * 1024 + (kt) * 128 + sb),              \
                    Ab + (size_t)(i * 256 + w * 64) * 16);                             \
            gload16(wsrc + ((size_t)(n0 + row) * 1024 + (kt) * 128 + sb),              \
                    Bb + (size_t)(i * 256 + w * 64) * 16);                             \
        }                                                                              \
    }

    STAGE(0, 0);
    for (int kt = 0; kt < 8; ++kt) {
        __syncthreads();
        if (kt < 7) STAGE(kt + 1, (kt + 1) & 1);
        const char* Ab = smem + (kt & 1) * 16384;
        const char* Bb = smem + 32768 + (kt & 1) * 16384;
#pragma unroll
        for (int ks = 0; ks < 2; ++ks) {
            bf16x8 a[4], bb[4];
#pragma unroll
            for (int i = 0; i < 4; ++i) {
                int r = wm * 64 + i * 16 + r15;
                int cb = (ks * 64 + hi * 16) ^ ((r & 7) << 4);
                a[i] = *(const bf16x8*)(Ab + r * 128 + cb);
            }
#pragma unroll
            for (int j = 0; j < 4; ++j) {
                int n = wn * 64 + j * 16 + r15;
                int cb = (ks * 64 + hi * 16) ^ ((n & 7) << 4);
                bb[j] = *(const bf16x8*)(Bb + n * 128 + cb);
            }
#pragma unroll
            for (int i = 0; i < 4; ++i)
#pragma unroll
                for (int j = 0; j < 4; ++j)
                    acc[i][j] = __builtin_amdgcn_mfma_f32_16x16x32_bf16(a[i], bb[j], acc[i][j], 0, 0, 0);
        }
    }
#undef STAGE

#pragma unroll
    for (int i = 0; i < 4; ++i) {
        int rowb = m0 + wm * 64 + i * 16 + hi * 4;
#pragma unroll
        for (int j = 0; j < 4; ++j) {
            int col = n0 + wn * 64 + j * 16 + r15;
#pragma unroll
            for (int r = 0; r < 4; ++r)
                sup1[(size_t)(rowb + r) * NHID + col] = f2bf(acc[i][j][r]);
        }
    }
}

// ---------------- propagate 1 (bf16 rows, packed edges, 8-unroll) ----------------
__global__ __launch_bounds__(256) void k_prop1(const unsigned short* __restrict__ sup1,
                                               const int* __restrict__ rowptr,
                                               const uint2* __restrict__ cedge,
                                               unsigned short* __restrict__ h1) {
    int gid = blockIdx.x * blockDim.x + threadIdx.x;
    int wid = gid >> 6;
    int lane = gid & 63;
    if (wid >= N_NODES) return;
    int beg = rowptr[wid], end = rowptr[wid + 1];
    float a0 = 0.f, a1 = 0.f, a2 = 0.f, a3 = 0.f;
    int e = beg;
    for (; e + 7 < end; e += 8) {
        uint2 ed[8];
#pragma unroll
        for (int q = 0; q < 8; ++q) ed[q] = cedge[e + q];
        uint2 r[8];
#pragma unroll
        for (int q = 0; q < 8; ++q)
            r[q] = *(const uint2*)(sup1 + (size_t)ed[q].x * NHID + lane * 4);
#pragma unroll
        for (int q = 0; q < 8; ++q) {
            float wq = __builtin_bit_cast(float, ed[q].y);
            float f0, f1, f2, f3;
            bf2x2(r[q].x, f0, f1);
            bf2x2(r[q].y, f2, f3);
            a0 += wq * f0; a1 += wq * f1; a2 += wq * f2; a3 += wq * f3;
        }
    }
    for (; e < end; ++e) {
        uint2 ed = cedge[e];
        float wq = __builtin_bit_cast(float, ed.y);
        uint2 rv = *(const uint2*)(sup1 + (size_t)ed.x * NHID + lane * 4);
        float f0, f1, f2, f3;
        bf2x2(rv.x, f0, f1);
        bf2x2(rv.y, f2, f3);
        a0 += wq * f0; a1 += wq * f1; a2 += wq * f2; a3 += wq * f3;
    }
    unsigned short o[4] = {f2bf(a0), f2bf(a1), f2bf(a2), f2bf(a3)};
    *(uint2*)(h1 + (size_t)wid * NHID + lane * 4) = *(const uint2*)o;
}

// ---------------- GEMM2 fused: sup2(bf16) = relu(h1 + b1) @ W2 ----------------
__global__ __launch_bounds__(256) void k_gemm2(const unsigned short* __restrict__ h1,
                                               const float* __restrict__ W2,
                                               const float* __restrict__ b1,
                                               unsigned short* __restrict__ sup2) {
    __shared__ float w2s[NHID * NCLASS];  // 40 KB
    __shared__ float b1s[NHID];
    __shared__ float rows[4][NHID];
    int t = threadIdx.x;
    for (int i = t; i < NHID * NCLASS; i += 256) w2s[i] = W2[i];
    b1s[t] = b1[t];
    __syncthreads();
    int wave = t >> 6, lane = t & 63;
    int gw = blockIdx.x * 4 + wave;
    int nw = gridDim.x * 4;
    for (int r = gw; r < N_NODES; r += nw) {
        uint2 v = *(const uint2*)(h1 + (size_t)r * NHID + lane * 4);
        float x0, x1, x2, x3;
        bf2x2(v.x, x0, x1); bf2x2(v.y, x2, x3);
        x0 = fmaxf(x0 + b1s[lane * 4 + 0], 0.f);
        x1 = fmaxf(x1 + b1s[lane * 4 + 1], 0.f);
        x2 = fmaxf(x2 + b1s[lane * 4 + 2], 0.f);
        x3 = fmaxf(x3 + b1s[lane * 4 + 3], 0.f);
        rows[wave][lane * 4 + 0] = x0;
        rows[wave][lane * 4 + 1] = x1;
        rows[wave][lane * 4 + 2] = x2;
        rows[wave][lane * 4 + 3] = x3;
        // wave-private LDS buffer: same-wave ds ops are ordered; no barrier needed
        if (lane < NCLASS) {
            float acc = 0.f;
#pragma unroll 8
            for (int k = 0; k < NHID; ++k) acc += rows[wave][k] * w2s[k * NCLASS + lane];
            sup2[(size_t)r * NCLASS + lane] = f2bf(acc);
        }
    }
}

// ---------------- propagate 2 + b2 + log_softmax (bf16 gather) ----------------
__global__ __launch_bounds__(256) void k_prop2(const unsigned short* __restrict__ sup2,
                                               const int* __restrict__ rowptr,
                                               const uint2* __restrict__ cedge,
                                               const float* __restrict__ b2,
                                               float* __restrict__ out) {
    int gid = blockIdx.x * blockDim.x + threadIdx.x;
    int wid = gid >> 6;
    int lane = gid & 63;
    if (wid >= N_NODES) return;
    int beg = rowptr[wid], end = rowptr[wid + 1];
    float acc = 0.f;
    int e = beg;
    for (; e + 3 < end; e += 4) {
        uint2 e0 = cedge[e], e1 = cedge[e + 1], e2 = cedge[e + 2], e3 = cedge[e + 3];
        if (lane < NCLASS) {
            float v0 = bf2f(sup2[(size_t)e0.x * NCLASS + lane]);
            float v1 = bf2f(sup2[(size_t)e1.x * NCLASS + lane]);
            float v2 = bf2f(sup2[(size_t)e2.x * NCLASS + lane]);
            float v3 = bf2f(sup2[(size_t)e3.x * NCLASS + lane]);
            acc += __builtin_bit_cast(float, e0.y) * v0 + __builtin_bit_cast(float, e1.y) * v1 +
                   __builtin_bit_cast(float, e2.y) * v2 + __builtin_bit_cast(float, e3.y) * v3;
        }
    }
    for (; e < end; ++e) {
        uint2 e0 = cedge[e];
        if (lane < NCLASS) acc += __builtin_bit_cast(float, e0.y) * bf2f(sup2[(size_t)e0.x * NCLASS + lane]);
    }
    float v = (lane < NCLASS) ? (acc + b2[lane]) : -INFINITY;
    float m = v;
#pragma unroll
    for (int off = 32; off >= 1; off >>= 1) m = fmaxf(m, __shfl_xor(m, off));
    float ex = (lane < NCLASS) ? expf(v - m) : 0.f;
    float s = ex;
#pragma unroll
    for (int off = 32; off >= 1; off >>= 1) s += __shfl_xor(s, off);
    if (lane < NCLASS) out[(size_t)wid * NCLASS + lane] = v - m - logf(s);
}

// ---------------- launch ----------------

extern "C" void kernel_launch(void* const* d_in, const int* in_sizes, int n_in,
                              void* d_out, int out_size, void* d_ws, size_t ws_size,
                              hipStream_t stream) {
    const float* x = (const float*)d_in[0];
    const int* ei = (const int*)d_in[1];
    const float* ew = (const float*)d_in[2];
    const float* W1 = (const float*)d_in[3];
    const float* b1 = (const float*)d_in[4];
    const float* W2 = (const float*)d_in[5];
    const float* b2 = (const float*)d_in[6];
    float* out = (float*)d_out;

    int E = in_sizes[1] / 2;
    const int* src = ei;
    const int* dst = ei + E;

    char* w = (char*)d_ws;
    size_t off = 0;
    auto alloc = [&](size_t bytes) {
        void* p = w + off;
        off += (bytes + 255) & ~(size_t)255;
        return p;
    };
    unsigned short* xb = (unsigned short*)alloc((size_t)M_PAD * NFEAT * 2);   // 102.5 MB
    unsigned short* w1t = (unsigned short*)alloc((size_t)NHID * NFEAT * 2);   // 256 KB
    unsigned short* sup1 = (unsigned short*)alloc((size_t)M_PAD * NHID * 2);  // 51.2 MB
    unsigned short* h1 = (unsigned short*)alloc((size_t)N_NODES * NHID * 2);  // 51.2 MB
    uint2* cedge = (uint2*)alloc((size_t)E * 8);                              // 25.6 MB
    int* rowptr = (int*)alloc((size_t)(N_NODES + 1) * 4);
    int* cursor = (int*)alloc((size_t)N_NODES * 4);
    int* deg = (int*)alloc((size_t)N_NODES * 4);
    int* bsum = (int*)alloc(2048);
    int* boff = (int*)alloc(2048);
    unsigned short* sup2 = (unsigned short*)xb;  // alias: xb dead after gemm1

    const int NB = (N_NODES + 255) / 256;  // 391

    hipMemsetAsync(deg, 0, (size_t)N_NODES * 4, stream);
    k_pre<<<HIST_BLOCKS + CVTX_BLOCKS + CVTW_BLOCKS, 256, 0, stream>>>(dst, deg, E, x, xb, W1, w1t);
    k_scan1<<<NB, 256, 0, stream>>>(deg, rowptr, bsum, N_NODES);
    k_scan2<<<1, 512, 0, stream>>>(bsum, boff, NB);
    k_scan3<<<NB, 256, 0, stream>>>(rowptr, boff, cursor, N_NODES);
    k_fill<<<2048, 256, 0, stream>>>(src, dst, ew, cursor, cedge, E);

    dim3 g1(M_PAD / 128, NHID / 128);
    k_gemm1<<<g1, 256, 0, stream>>>(xb, w1t, sup1);
    k_prop1<<<(N_NODES + 3) / 4, 256, 0, stream>>>(sup1, rowptr, cedge, h1);
    k_gemm2<<<2048, 256, 0, stream>>>(h1, W2, b1, sup2);
    k_prop2<<<(N_NODES + 3) / 4, 256, 0, stream>>>(sup2, rowptr, cedge, b2, out);
}

// Round 4
// 962.573 us; speedup vs baseline: 1.5353x; 1.0382x over previous
//
#include <hip/hip_runtime.h>
#include <math.h>

#define N_NODES 100000
#define M_PAD 100096  /* 782*128 */
#define NFEAT 512
#define NHID 256
#define NCLASS 40
#define CPAD 32  /* counter padding: one counter per 128B line */

typedef __attribute__((ext_vector_type(8))) short bf16x8;
typedef __attribute__((ext_vector_type(4))) float f32x4;

__device__ __forceinline__ unsigned short f2bf(float f) {
    unsigned int u = __builtin_bit_cast(unsigned int, f);
    u += 0x7fffu + ((u >> 16) & 1u);  // RNE
    return (unsigned short)(u >> 16);
}
__device__ __forceinline__ float bf2f(unsigned short u) {
    return __builtin_bit_cast(float, (unsigned int)u << 16);
}
__device__ __forceinline__ void bf2x2(unsigned int u, float& f0, float& f1) {
    f0 = __builtin_bit_cast(float, u << 16);
    f1 = __builtin_bit_cast(float, u & 0xffff0000u);
}
__device__ __forceinline__ void gload16(const void* g, void* l) {
    __builtin_amdgcn_global_load_lds(
        (const __attribute__((address_space(1))) unsigned int*)g,
        (__attribute__((address_space(3))) unsigned int*)l, 16, 0, 0);
}

// ---------------- fused pre-pass: hist (blocks 0..2047) + cvt_x + cvt_w1 ----------------
#define HIST_BLOCKS 2048
#define CVTX_BLOCKS 25024 /* M_PAD*512/8/256 */
#define CVTW_BLOCKS 512   /* 256*512/256 */

__global__ __launch_bounds__(256) void k_pre(const int* __restrict__ dst, int* __restrict__ deg,
                                             int E, const float* __restrict__ x,
                                             unsigned short* __restrict__ xb,
                                             const float* __restrict__ W1,
                                             unsigned short* __restrict__ w1t) {
    int b = blockIdx.x;
    int t = threadIdx.x;
    if (b < HIST_BLOCKS) {
        // histogram of dst into padded deg (pre-zeroed); latency-bound, runs first
        int i = b * 256 + t;
        int stride = HIST_BLOCKS * 256;
        for (; i < E; i += stride) atomicAdd(&deg[(size_t)dst[i] * CPAD], 1);
    } else if (b < HIST_BLOCKS + CVTX_BLOCKS) {
        // x f32 -> xb bf16, pad rows zero; 8 elems/thread
        size_t i = ((size_t)(b - HIST_BLOCKS) * 256 + t) * 8;
        const size_t real = (size_t)N_NODES * NFEAT;
        unsigned short o[8];
        if (i < real) {
            float4 v0 = *(const float4*)(x + i);
            float4 v1 = *(const float4*)(x + i + 4);
            o[0]=f2bf(v0.x); o[1]=f2bf(v0.y); o[2]=f2bf(v0.z); o[3]=f2bf(v0.w);
            o[4]=f2bf(v1.x); o[5]=f2bf(v1.y); o[6]=f2bf(v1.z); o[7]=f2bf(v1.w);
        } else {
            for (int j = 0; j < 8; ++j) o[j] = 0;
        }
        *(uint4*)(xb + i) = *(const uint4*)o;
    } else {
        // W1 [512][256] -> w1t [256][512] transposed bf16
        int idx = (b - HIST_BLOCKS - CVTX_BLOCKS) * 256 + t;
        int n = idx >> 9, k = idx & 511;
        w1t[idx] = f2bf(W1[(size_t)k * NHID + n]);
    }
}

// ---------------- scans ----------------

__global__ void k_scan1(const int* __restrict__ deg, int* __restrict__ rowptr,
                        int* __restrict__ bsum, int n) {
    __shared__ int sm[256];
    int t = threadIdx.x;
    int idx = blockIdx.x * 256 + t;
    int v = (idx < n) ? deg[(size_t)idx * CPAD] : 0;
    sm[t] = v;
    __syncthreads();
    for (int off = 1; off < 256; off <<= 1) {
        int a = (t >= off) ? sm[t - off] : 0;
        __syncthreads();
        sm[t] += a;
        __syncthreads();
    }
    if (idx < n) rowptr[idx + 1] = sm[t];
    if (t == 255) bsum[blockIdx.x] = sm[255];
    if (idx == 0) rowptr[0] = 0;
}

__global__ void k_scan2(const int* __restrict__ bsum, int* __restrict__ boff, int nb) {
    __shared__ int sm[512];
    int t = threadIdx.x;
    int v = (t < nb) ? bsum[t] : 0;
    sm[t] = v;
    __syncthreads();
    for (int off = 1; off < 512; off <<= 1) {
        int a = (t >= off) ? sm[t - off] : 0;
        __syncthreads();
        sm[t] += a;
        __syncthreads();
    }
    if (t < nb) boff[t] = sm[t] - v;
}

__global__ void k_scan3(int* __restrict__ rowptr, const int* __restrict__ boff,
                        int* __restrict__ cursor, int n) {
    int idx = blockIdx.x * blockDim.x + threadIdx.x;
    if (idx < n) {
        int f = rowptr[idx + 1] + boff[idx >> 8];
        rowptr[idx + 1] = f;
        if (idx + 1 < n) cursor[(size_t)(idx + 1) * CPAD] = f;
        if (idx == 0) cursor[0] = 0;
    }
}

// ---------------- fill: packed (src, w) 8B scatter, padded cursor ----------------

__global__ void k_fill(const int* __restrict__ src, const int* __restrict__ dst,
                       const float* __restrict__ ew, int* __restrict__ cursor,
                       uint2* __restrict__ cedge, int E) {
    int i = blockIdx.x * blockDim.x + threadIdx.x;
    int stride = gridDim.x * blockDim.x;
    for (; i < E; i += stride) {
        int d = dst[i];
        int p = atomicAdd(&cursor[(size_t)d * CPAD], 1);
        cedge[p] = make_uint2((unsigned)src[i], __builtin_bit_cast(unsigned, ew[i]));
    }
}

// ---------------- GEMM1 (MFMA bf16): sup1 = xb @ W1 ----------------
__global__ __launch_bounds__(256) void k_gemm1(const unsigned short* __restrict__ xb,
                                               const unsigned short* __restrict__ w1t,
                                               unsigned short* __restrict__ sup1) {
    __shared__ char smem[65536];  // A: 2x16KB @0, B: 2x16KB @32768
    const int t = threadIdx.x;
    const int w = t >> 6, lane = t & 63;
    const int m0 = blockIdx.x * 128;
    const int n0 = blockIdx.y * 128;
    const int wm = w >> 1, wn = w & 1;
    const int r15 = lane & 15, hi = lane >> 4;

    f32x4 acc[4][4];
#pragma unroll
    for (int i = 0; i < 4; ++i)
#pragma unroll
        for (int j = 0; j < 4; ++j) acc[i][j] = (f32x4){0.f, 0.f, 0.f, 0.f};

    const char* xsrc = (const char*)xb;
    const char* wsrc = (const char*)w1t;

#define STAGE(kt, b)                                                                   \
    {                                                                                  \
        char* Ab = smem + (b) * 16384;                                                 \
        char* Bb = smem + 32768 + (b) * 16384;                                         \
        _Pragma("unroll") for (int i = 0; i < 4; ++i) {                                \
            int c = i * 256 + w * 64 + lane;                                           \
            int row = c >> 3;                                                          \
            int sb = ((c & 7) * 16) ^ ((row & 7) << 4);                                \
            gload16(xsrc + ((size_t)(m0 + row) * 1024 + (kt) * 128 + sb),              \
                    Ab + (size_t)(i * 256 + w * 64) * 16);                             \
            gload16(wsrc + ((size_t)(n0 + row) * 1024 + (kt) * 128 + sb),              \
                    Bb + (size_t)(i * 256 + w * 64) * 16);                             \
        }                                                                              \
    }

    STAGE(0, 0);
    for (int kt = 0; kt < 8; ++kt) {
        __syncthreads();
        if (kt < 7) STAGE(kt + 1, (kt + 1) & 1);
        const char* Ab = smem + (kt & 1) * 16384;
        const char* Bb = smem + 32768 + (kt & 1) * 16384;
#pragma unroll
        for (int ks = 0; ks < 2; ++ks) {
            bf16x8 a[4], bb[4];
#pragma unroll
            for (int i = 0; i < 4; ++i) {
                int r = wm * 64 + i * 16 + r15;
                int cb = (ks * 64 + hi * 16) ^ ((r & 7) << 4);
                a[i] = *(const bf16x8*)(Ab + r * 128 + cb);
            }
#pragma unroll
            for (int j = 0; j < 4; ++j) {
                int n = wn * 64 + j * 16 + r15;
                int cb = (ks * 64 + hi * 16) ^ ((n & 7) << 4);
                bb[j] = *(const bf16x8*)(Bb + n * 128 + cb);
            }
#pragma unroll
            for (int i = 0; i < 4; ++i)
#pragma unroll
                for (int j = 0; j < 4; ++j)
                    acc[i][j] = __builtin_amdgcn_mfma_f32_16x16x32_bf16(a[i], bb[j], acc[i][j], 0, 0, 0);
        }
    }
#undef STAGE

#pragma unroll
    for (int i = 0; i < 4; ++i) {
        int rowb = m0 + wm * 64 + i * 16 + hi * 4;
#pragma unroll
        for (int j = 0; j < 4; ++j) {
            int col = n0 + wn * 64 + j * 16 + r15;
#pragma unroll
            for (int r = 0; r < 4; ++r)
                sup1[(size_t)(rowb + r) * NHID + col] = f2bf(acc[i][j][r]);
        }
    }
}

// ---------------- propagate 1 (bf16 rows, packed edges, 8-unroll) ----------------
__global__ __launch_bounds__(256) void k_prop1(const unsigned short* __restrict__ sup1,
                                               const int* __restrict__ rowptr,
                                               const uint2* __restrict__ cedge,
                                               unsigned short* __restrict__ h1) {
    int gid = blockIdx.x * blockDim.x + threadIdx.x;
    int wid = gid >> 6;
    int lane = gid & 63;
    if (wid >= N_NODES) return;
    int beg = rowptr[wid], end = rowptr[wid + 1];
    float a0 = 0.f, a1 = 0.f, a2 = 0.f, a3 = 0.f;
    int e = beg;
    for (; e + 7 < end; e += 8) {
        uint2 ed[8];
#pragma unroll
        for (int q = 0; q < 8; ++q) ed[q] = cedge[e + q];
        uint2 r[8];
#pragma unroll
        for (int q = 0; q < 8; ++q)
            r[q] = *(const uint2*)(sup1 + (size_t)ed[q].x * NHID + lane * 4);
#pragma unroll
        for (int q = 0; q < 8; ++q) {
            float wq = __builtin_bit_cast(float, ed[q].y);
            float f0, f1, f2, f3;
            bf2x2(r[q].x, f0, f1);
            bf2x2(r[q].y, f2, f3);
            a0 += wq * f0; a1 += wq * f1; a2 += wq * f2; a3 += wq * f3;
        }
    }
    for (; e < end; ++e) {
        uint2 ed = cedge[e];
        float wq = __builtin_bit_cast(float, ed.y);
        uint2 rv = *(const uint2*)(sup1 + (size_t)ed.x * NHID + lane * 4);
        float f0, f1, f2, f3;
        bf2x2(rv.x, f0, f1);
        bf2x2(rv.y, f2, f3);
        a0 += wq * f0; a1 += wq * f1; a2 += wq * f2; a3 += wq * f3;
    }
    unsigned short o[4] = {f2bf(a0), f2bf(a1), f2bf(a2), f2bf(a3)};
    *(uint2*)(h1 + (size_t)wid * NHID + lane * 4) = *(const uint2*)o;
}

// ---------------- GEMM2 fused: sup2(bf16) = relu(h1 + b1) @ W2 ----------------
__global__ __launch_bounds__(256) void k_gemm2(const unsigned short* __restrict__ h1,
                                               const float* __restrict__ W2,
                                               const float* __restrict__ b1,
                                               unsigned short* __restrict__ sup2) {
    __shared__ float w2s[NHID * NCLASS];  // 40 KB
    __shared__ float b1s[NHID];
    __shared__ float rows[4][NHID];
    int t = threadIdx.x;
    for (int i = t; i < NHID * NCLASS; i += 256) w2s[i] = W2[i];
    b1s[t] = b1[t];
    __syncthreads();
    int wave = t >> 6, lane = t & 63;
    int gw = blockIdx.x * 4 + wave;
    int nw = gridDim.x * 4;
    for (int r = gw; r < N_NODES; r += nw) {
        uint2 v = *(const uint2*)(h1 + (size_t)r * NHID + lane * 4);
        float x0, x1, x2, x3;
        bf2x2(v.x, x0, x1); bf2x2(v.y, x2, x3);
        x0 = fmaxf(x0 + b1s[lane * 4 + 0], 0.f);
        x1 = fmaxf(x1 + b1s[lane * 4 + 1], 0.f);
        x2 = fmaxf(x2 + b1s[lane * 4 + 2], 0.f);
        x3 = fmaxf(x3 + b1s[lane * 4 + 3], 0.f);
        rows[wave][lane * 4 + 0] = x0;
        rows[wave][lane * 4 + 1] = x1;
        rows[wave][lane * 4 + 2] = x2;
        rows[wave][lane * 4 + 3] = x3;
        // wave-private LDS buffer: same-wave ds ops are ordered; no barrier needed
        if (lane < NCLASS) {
            float acc = 0.f;
#pragma unroll 8
            for (int k = 0; k < NHID; ++k) acc += rows[wave][k] * w2s[k * NCLASS + lane];
            sup2[(size_t)r * NCLASS + lane] = f2bf(acc);
        }
    }
}

// ---------------- propagate 2 + b2 + log_softmax (bf16 gather) ----------------
__global__ __launch_bounds__(256) void k_prop2(const unsigned short* __restrict__ sup2,
                                               const int* __restrict__ rowptr,
                                               const uint2* __restrict__ cedge,
                                               const float* __restrict__ b2,
                                               float* __restrict__ out) {
    int gid = blockIdx.x * blockDim.x + threadIdx.x;
    int wid = gid >> 6;
    int lane = gid & 63;
    if (wid >= N_NODES) return;
    int beg = rowptr[wid], end = rowptr[wid + 1];
    float acc = 0.f;
    int e = beg;
    for (; e + 3 < end; e += 4) {
        uint2 e0 = cedge[e], e1 = cedge[e + 1], e2 = cedge[e + 2], e3 = cedge[e + 3];
        if (lane < NCLASS) {
            float v0 = bf2f(sup2[(size_t)e0.x * NCLASS + lane]);
            float v1 = bf2f(sup2[(size_t)e1.x * NCLASS + lane]);
            float v2 = bf2f(sup2[(size_t)e2.x * NCLASS + lane]);
            float v3 = bf2f(sup2[(size_t)e3.x * NCLASS + lane]);
            acc += __builtin_bit_cast(float, e0.y) * v0 + __builtin_bit_cast(float, e1.y) * v1 +
                   __builtin_bit_cast(float, e2.y) * v2 + __builtin_bit_cast(float, e3.y) * v3;
        }
    }
    for (; e < end; ++e) {
        uint2 e0 = cedge[e];
        if (lane < NCLASS) acc += __builtin_bit_cast(float, e0.y) * bf2f(sup2[(size_t)e0.x * NCLASS + lane]);
    }
    float v = (lane < NCLASS) ? (acc + b2[lane]) : -INFINITY;
    float m = v;
#pragma unroll
    for (int off = 32; off >= 1; off >>= 1) m = fmaxf(m, __shfl_xor(m, off));
    float ex = (lane < NCLASS) ? expf(v - m) : 0.f;
    float s = ex;
#pragma unroll
    for (int off = 32; off >= 1; off >>= 1) s += __shfl_xor(s, off);
    if (lane < NCLASS) out[(size_t)wid * NCLASS + lane] = v - m - logf(s);
}

// ---------------- launch ----------------

extern "C" void kernel_launch(void* const* d_in, const int* in_sizes, int n_in,
                              void* d_out, int out_size, void* d_ws, size_t ws_size,
                              hipStream_t stream) {
    const float* x = (const float*)d_in[0];
    const int* ei = (const int*)d_in[1];
    const float* ew = (const float*)d_in[2];
    const float* W1 = (const float*)d_in[3];
    const float* b1 = (const float*)d_in[4];
    const float* W2 = (const float*)d_in[5];
    const float* b2 = (const float*)d_in[6];
    float* out = (float*)d_out;

    int E = in_sizes[1] / 2;
    const int* src = ei;
    const int* dst = ei + E;

    char* w = (char*)d_ws;
    size_t off = 0;
    auto alloc = [&](size_t bytes) {
        void* p = w + off;
        off += (bytes + 255) & ~(size_t)255;
        return p;
    };
    unsigned short* xb = (unsigned short*)alloc((size_t)M_PAD * NFEAT * 2);   // 102.5 MB
    unsigned short* w1t = (unsigned short*)alloc((size_t)NHID * NFEAT * 2);   // 256 KB
    unsigned short* sup1 = (unsigned short*)alloc((size_t)M_PAD * NHID * 2);  // 51.2 MB
    unsigned short* h1 = (unsigned short*)alloc((size_t)N_NODES * NHID * 2);  // 51.2 MB
    uint2* cedge = (uint2*)alloc((size_t)E * 8);                              // 25.6 MB
    int* rowptr = (int*)alloc((size_t)(N_NODES + 1) * 4);
    int* bsum = (int*)alloc(2048);
    int* boff = (int*)alloc(2048);
    unsigned short* sup2 = (unsigned short*)xb;  // alias: xb dead after gemm1
    // padded counters (12.8 MB each) alias h1's buffer: deg dead after scan1,
    // cursor dead after k_fill, h1 first written in prop1 (after k_fill).
    int* deg = (int*)h1;
    int* cursor = (int*)((char*)h1 + (size_t)N_NODES * CPAD * 4 + 256);

    const int NB = (N_NODES + 255) / 256;  // 391

    hipMemsetAsync(deg, 0, (size_t)N_NODES * CPAD * 4, stream);
    k_pre<<<HIST_BLOCKS + CVTX_BLOCKS + CVTW_BLOCKS, 256, 0, stream>>>(dst, deg, E, x, xb, W1, w1t);
    k_scan1<<<NB, 256, 0, stream>>>(deg, rowptr, bsum, N_NODES);
    k_scan2<<<1, 512, 0, stream>>>(bsum, boff, NB);
    k_scan3<<<NB, 256, 0, stream>>>(rowptr, boff, cursor, N_NODES);
    k_fill<<<4096, 256, 0, stream>>>(src, dst, ew, cursor, cedge, E);

    dim3 g1(M_PAD / 128, NHID / 128);
    k_gemm1<<<g1, 256, 0, stream>>>(xb, w1t, sup1);
    k_prop1<<<(N_NODES + 3) / 4, 256, 0, stream>>>(sup1, rowptr, cedge, h1);
    k_gemm2<<<2048, 256, 0, stream>>>(h1, W2, b1, sup2);
    k_prop2<<<(N_NODES + 3) / 4, 256, 0, stream>>>(sup2, rowptr, cedge, b2, out);
}

// Round 5
// 841.613 us; speedup vs baseline: 1.7560x; 1.1437x over previous
//
#include <hip/hip_runtime.h>
#include <math.h>

#define N_NODES 100000
#define M_PAD 100096  /* 782*128 */
#define NFEAT 512
#define NHID 256
#define NCLASS 40

#define NBKT 250       /* coarse buckets */
#define NPB 400        /* nodes per bucket: 250*400 = 100000 exactly */
#define BINA_CHUNK 6144

typedef __attribute__((ext_vector_type(8))) short bf16x8;
typedef __attribute__((ext_vector_type(4))) float f32x4;

__device__ __forceinline__ unsigned short f2bf(float f) {
    unsigned int u = __builtin_bit_cast(unsigned int, f);
    u += 0x7fffu + ((u >> 16) & 1u);  // RNE
    return (unsigned short)(u >> 16);
}
__device__ __forceinline__ float bf2f(unsigned short u) {
    return __builtin_bit_cast(float, (unsigned int)u << 16);
}
__device__ __forceinline__ void bf2x2(unsigned int u, float& f0, float& f1) {
    f0 = __builtin_bit_cast(float, u << 16);
    f1 = __builtin_bit_cast(float, u & 0xffff0000u);
}
__device__ __forceinline__ void gload16(const void* g, void* l) {
    __builtin_amdgcn_global_load_lds(
        (const __attribute__((address_space(1))) unsigned int*)g,
        (__attribute__((address_space(3))) unsigned int*)l, 16, 0, 0);
}

// ---------------- fused pre-pass: hist (blocks 0..2047) + cvt_x + cvt_w1 ----------------
#define HIST_BLOCKS 2048
#define CVTX_BLOCKS 25024 /* M_PAD*512/8/256 */
#define CVTW_BLOCKS 512   /* 256*512/256 */

__global__ __launch_bounds__(256) void k_pre(const int* __restrict__ dst, int* __restrict__ deg,
                                             int E, const float* __restrict__ x,
                                             unsigned short* __restrict__ xb,
                                             const float* __restrict__ W1,
                                             unsigned short* __restrict__ w1t) {
    int b = blockIdx.x;
    int t = threadIdx.x;
    if (b < HIST_BLOCKS) {
        // histogram of dst (deg pre-zeroed); vectorized int4 reads
        int tid = b * 256 + t;
        int stride4 = HIST_BLOCKS * 256 * 4;
        for (int i = tid * 4; i + 3 < E; i += stride4) {
            int4 d4 = *(const int4*)(dst + i);
            atomicAdd(&deg[d4.x], 1);
            atomicAdd(&deg[d4.y], 1);
            atomicAdd(&deg[d4.z], 1);
            atomicAdd(&deg[d4.w], 1);
        }
        if (tid == 0) {
            for (int i = E & ~3; i < E; ++i) atomicAdd(&deg[dst[i]], 1);
        }
    } else if (b < HIST_BLOCKS + CVTX_BLOCKS) {
        // x f32 -> xb bf16, pad rows zero; 8 elems/thread
        size_t i = ((size_t)(b - HIST_BLOCKS) * 256 + t) * 8;
        const size_t real = (size_t)N_NODES * NFEAT;
        unsigned short o[8];
        if (i < real) {
            float4 v0 = *(const float4*)(x + i);
            float4 v1 = *(const float4*)(x + i + 4);
            o[0]=f2bf(v0.x); o[1]=f2bf(v0.y); o[2]=f2bf(v0.z); o[3]=f2bf(v0.w);
            o[4]=f2bf(v1.x); o[5]=f2bf(v1.y); o[6]=f2bf(v1.z); o[7]=f2bf(v1.w);
        } else {
            for (int j = 0; j < 8; ++j) o[j] = 0;
        }
        *(uint4*)(xb + i) = *(const uint4*)o;
    } else {
        // W1 [512][256] -> w1t [256][512] transposed bf16
        int idx = (b - HIST_BLOCKS - CVTX_BLOCKS) * 256 + t;
        int n = idx >> 9, k = idx & 511;
        w1t[idx] = f2bf(W1[(size_t)k * NHID + n]);
    }
}

// ---------------- scans ----------------

__global__ void k_scan1(const int* __restrict__ deg, int* __restrict__ rowptr,
                        int* __restrict__ bsum, int n) {
    __shared__ int sm[256];
    int t = threadIdx.x;
    int idx = blockIdx.x * 256 + t;
    int v = (idx < n) ? deg[idx] : 0;
    sm[t] = v;
    __syncthreads();
    for (int off = 1; off < 256; off <<= 1) {
        int a = (t >= off) ? sm[t - off] : 0;
        __syncthreads();
        sm[t] += a;
        __syncthreads();
    }
    if (idx < n) rowptr[idx + 1] = sm[t];
    if (t == 255) bsum[blockIdx.x] = sm[255];
    if (idx == 0) rowptr[0] = 0;
}

__global__ void k_scan2(const int* __restrict__ bsum, int* __restrict__ boff, int nb) {
    __shared__ int sm[512];
    int t = threadIdx.x;
    int v = (t < nb) ? bsum[t] : 0;
    sm[t] = v;
    __syncthreads();
    for (int off = 1; off < 512; off <<= 1) {
        int a = (t >= off) ? sm[t - off] : 0;
        __syncthreads();
        sm[t] += a;
        __syncthreads();
    }
    if (t < nb) boff[t] = sm[t] - v;
}

// finalize rowptr; init coarse-bucket cursors bcur[b] = rowptr[b*NPB]
__global__ void k_scan3(int* __restrict__ rowptr, const int* __restrict__ boff,
                        int* __restrict__ bcur, int n) {
    int idx = blockIdx.x * blockDim.x + threadIdx.x;
    if (idx < n) {
        int f = rowptr[idx + 1] + boff[idx >> 8];
        rowptr[idx + 1] = f;
        int p = idx + 1;
        if ((p % NPB) == 0 && (p / NPB) < NBKT) bcur[p / NPB] = f;
        if (idx == 0) bcur[0] = 0;
    }
}

// ---------------- binA: LDS counting-sort chunk into 250 buckets, coalesced drain ----------------
__global__ __launch_bounds__(256) void k_binA(const int* __restrict__ src,
                                              const int* __restrict__ dst,
                                              const float* __restrict__ ew,
                                              int* __restrict__ bcur,
                                              uint2* __restrict__ tmp, int E) {
    __shared__ uint2 sorted[BINA_CHUNK];        // 48 KB
    __shared__ unsigned char bkt8[BINA_CHUNK];  // 6 KB
    __shared__ int cnt[256], startv[256], offv[256], gb[256];
    int t = threadIdx.x;
    int c0 = blockIdx.x * BINA_CHUNK;
    int n = min(BINA_CHUNK, E - c0);
    cnt[t] = 0;
    __syncthreads();
    // pass 1: count
    for (int j = t; j < n; j += 256) {
        int b = (unsigned)dst[c0 + j] / NPB;
        atomicAdd(&cnt[b], 1);
    }
    __syncthreads();
    // inclusive scan of cnt (256-wide Hillis-Steele)
    int v = cnt[t];
    startv[t] = v;
    __syncthreads();
    for (int o = 1; o < 256; o <<= 1) {
        int a = (t >= o) ? startv[t - o] : 0;
        __syncthreads();
        startv[t] += a;
        __syncthreads();
    }
    int ex = startv[t] - v;  // exclusive start
    __syncthreads();
    startv[t] = ex;
    offv[t] = ex;
    if (t < NBKT) gb[t] = (v > 0) ? atomicAdd(&bcur[t], v) : 0;
    __syncthreads();
    // pass 2: rank + place into LDS (sorted by bucket)
    for (int j = t; j < n; j += 256) {
        int d = dst[c0 + j];
        int b = (unsigned)d / NPB;
        int dl = d - b * NPB;  // < 400, 9 bits
        int r = atomicAdd(&offv[b], 1);
        sorted[r] = make_uint2((unsigned)src[c0 + j] | ((unsigned)dl << 17),
                               __builtin_bit_cast(unsigned, ew[c0 + j]));
        bkt8[r] = (unsigned char)b;
    }
    __syncthreads();
    // drain: linear over sorted -> coalesced bursts per bucket region
    for (int j = t; j < n; j += 256) {
        int b = bkt8[j];
        tmp[gb[b] + (j - startv[b])] = sorted[j];
    }
}

// ---------------- binB: per-bucket fine scatter within block-private L2 window ----------------
__global__ __launch_bounds__(256) void k_binB(const uint2* __restrict__ tmp,
                                              const int* __restrict__ rowptr,
                                              uint2* __restrict__ cedge) {
    __shared__ int nc[NPB];
    int b = blockIdx.x;
    int t = threadIdx.x;
    int n0 = b * NPB;
    for (int nn = t; nn < NPB; nn += 256) nc[nn] = rowptr[n0 + nn];
    __syncthreads();
    int beg = rowptr[n0];
    int end = rowptr[n0 + NPB];
    for (int j = beg + t; j < end; j += 256) {
        uint2 e = tmp[j];
        int dl = e.x >> 17;
        int addr = atomicAdd(&nc[dl], 1);
        cedge[addr] = make_uint2(e.x & 0x1FFFFu, e.y);
    }
}

// ---------------- GEMM1 (MFMA bf16): sup1 = xb @ W1 ----------------
__global__ __launch_bounds__(256) void k_gemm1(const unsigned short* __restrict__ xb,
                                               const unsigned short* __restrict__ w1t,
                                               unsigned short* __restrict__ sup1) {
    __shared__ char smem[65536];  // A: 2x16KB @0, B: 2x16KB @32768
    const int t = threadIdx.x;
    const int w = t >> 6, lane = t & 63;
    const int m0 = blockIdx.x * 128;
    const int n0 = blockIdx.y * 128;
    const int wm = w >> 1, wn = w & 1;
    const int r15 = lane & 15, hi = lane >> 4;

    f32x4 acc[4][4];
#pragma unroll
    for (int i = 0; i < 4; ++i)
#pragma unroll
        for (int j = 0; j < 4; ++j) acc[i][j] = (f32x4){0.f, 0.f, 0.f, 0.f};

    const char* xsrc = (const char*)xb;
    const char* wsrc = (const char*)w1t;

#define STAGE(kt, b)                                                                   \
    {                                                                                  \
        char* Ab = smem + (b) * 16384;                                                 \
        char* Bb = smem + 32768 + (b) * 16384;                                         \
        _Pragma("unroll") for (int i = 0; i < 4; ++i) {                                \
            int c = i * 256 + w * 64 + lane;                                           \
            int row = c >> 3;                                                          \
            int sb = ((c & 7) * 16) ^ ((row & 7) << 4);                                \
            gload16(xsrc + ((size_t)(m0 + row) * 1024 + (kt) * 128 + sb),              \
                    Ab + (size_t)(i * 256 + w * 64) * 16);                             \
            gload16(wsrc + ((size_t)(n0 + row) * 1024 + (kt) * 128 + sb),              \
                    Bb + (size_t)(i * 256 + w * 64) * 16);                             \
        }                                                                              \
    }

    STAGE(0, 0);
    for (int kt = 0; kt < 8; ++kt) {
        __syncthreads();
        if (kt < 7) STAGE(kt + 1, (kt + 1) & 1);
        const char* Ab = smem + (kt & 1) * 16384;
        const char* Bb = smem + 32768 + (kt & 1) * 16384;
#pragma unroll
        for (int ks = 0; ks < 2; ++ks) {
            bf16x8 a[4], bb[4];
#pragma unroll
            for (int i = 0; i < 4; ++i) {
                int r = wm * 64 + i * 16 + r15;
                int cb = (ks * 64 + hi * 16) ^ ((r & 7) << 4);
                a[i] = *(const bf16x8*)(Ab + r * 128 + cb);
            }
#pragma unroll
            for (int j = 0; j < 4; ++j) {
                int n = wn * 64 + j * 16 + r15;
                int cb = (ks * 64 + hi * 16) ^ ((n & 7) << 4);
                bb[j] = *(const bf16x8*)(Bb + n * 128 + cb);
            }
#pragma unroll
            for (int i = 0; i < 4; ++i)
#pragma unroll
                for (int j = 0; j < 4; ++j)
                    acc[i][j] = __builtin_amdgcn_mfma_f32_16x16x32_bf16(a[i], bb[j], acc[i][j], 0, 0, 0);
        }
    }
#undef STAGE

#pragma unroll
    for (int i = 0; i < 4; ++i) {
        int rowb = m0 + wm * 64 + i * 16 + hi * 4;
#pragma unroll
        for (int j = 0; j < 4; ++j) {
            int col = n0 + wn * 64 + j * 16 + r15;
#pragma unroll
            for (int r = 0; r < 4; ++r)
                sup1[(size_t)(rowb + r) * NHID + col] = f2bf(acc[i][j][r]);
        }
    }
}

// ---------------- propagate 1 (bf16 rows, packed edges, 8-unroll) ----------------
__global__ __launch_bounds__(256) void k_prop1(const unsigned short* __restrict__ sup1,
                                               const int* __restrict__ rowptr,
                                               const uint2* __restrict__ cedge,
                                               unsigned short* __restrict__ h1) {
    int gid = blockIdx.x * blockDim.x + threadIdx.x;
    int wid = gid >> 6;
    int lane = gid & 63;
    if (wid >= N_NODES) return;
    int beg = rowptr[wid], end = rowptr[wid + 1];
    float a0 = 0.f, a1 = 0.f, a2 = 0.f, a3 = 0.f;
    int e = beg;
    for (; e + 7 < end; e += 8) {
        uint2 ed[8];
#pragma unroll
        for (int q = 0; q < 8; ++q) ed[q] = cedge[e + q];
        uint2 r[8];
#pragma unroll
        for (int q = 0; q < 8; ++q)
            r[q] = *(const uint2*)(sup1 + (size_t)ed[q].x * NHID + lane * 4);
#pragma unroll
        for (int q = 0; q < 8; ++q) {
            float wq = __builtin_bit_cast(float, ed[q].y);
            float f0, f1, f2, f3;
            bf2x2(r[q].x, f0, f1);
            bf2x2(r[q].y, f2, f3);
            a0 += wq * f0; a1 += wq * f1; a2 += wq * f2; a3 += wq * f3;
        }
    }
    for (; e < end; ++e) {
        uint2 ed = cedge[e];
        float wq = __builtin_bit_cast(float, ed.y);
        uint2 rv = *(const uint2*)(sup1 + (size_t)ed.x * NHID + lane * 4);
        float f0, f1, f2, f3;
        bf2x2(rv.x, f0, f1);
        bf2x2(rv.y, f2, f3);
        a0 += wq * f0; a1 += wq * f1; a2 += wq * f2; a3 += wq * f3;
    }
    unsigned short o[4] = {f2bf(a0), f2bf(a1), f2bf(a2), f2bf(a3)};
    *(uint2*)(h1 + (size_t)wid * NHID + lane * 4) = *(const uint2*)o;
}

// ---------------- GEMM2 fused: sup2(bf16) = relu(h1 + b1) @ W2 ----------------
__global__ __launch_bounds__(256) void k_gemm2(const unsigned short* __restrict__ h1,
                                               const float* __restrict__ W2,
                                               const float* __restrict__ b1,
                                               unsigned short* __restrict__ sup2) {
    __shared__ float w2s[NHID * NCLASS];  // 40 KB
    __shared__ float b1s[NHID];
    __shared__ float rows[4][NHID];
    int t = threadIdx.x;
    for (int i = t; i < NHID * NCLASS; i += 256) w2s[i] = W2[i];
    b1s[t] = b1[t];
    __syncthreads();
    int wave = t >> 6, lane = t & 63;
    int gw = blockIdx.x * 4 + wave;
    int nw = gridDim.x * 4;
    for (int r = gw; r < N_NODES; r += nw) {
        uint2 v = *(const uint2*)(h1 + (size_t)r * NHID + lane * 4);
        float x0, x1, x2, x3;
        bf2x2(v.x, x0, x1); bf2x2(v.y, x2, x3);
        x0 = fmaxf(x0 + b1s[lane * 4 + 0], 0.f);
        x1 = fmaxf(x1 + b1s[lane * 4 + 1], 0.f);
        x2 = fmaxf(x2 + b1s[lane * 4 + 2], 0.f);
        x3 = fmaxf(x3 + b1s[lane * 4 + 3], 0.f);
        rows[wave][lane * 4 + 0] = x0;
        rows[wave][lane * 4 + 1] = x1;
        rows[wave][lane * 4 + 2] = x2;
        rows[wave][lane * 4 + 3] = x3;
        // wave-private LDS buffer: same-wave ds ops are ordered; no barrier needed
        if (lane < NCLASS) {
            float acc = 0.f;
#pragma unroll 8
            for (int k = 0; k < NHID; ++k) acc += rows[wave][k] * w2s[k * NCLASS + lane];
            sup2[(size_t)r * NCLASS + lane] = f2bf(acc);
        }
    }
}

// ---------------- propagate 2 + b2 + log_softmax (bf16 gather) ----------------
__global__ __launch_bounds__(256) void k_prop2(const unsigned short* __restrict__ sup2,
                                               const int* __restrict__ rowptr,
                                               const uint2* __restrict__ cedge,
                                               const float* __restrict__ b2,
                                               float* __restrict__ out) {
    int gid = blockIdx.x * blockDim.x + threadIdx.x;
    int wid = gid >> 6;
    int lane = gid & 63;
    if (wid >= N_NODES) return;
    int beg = rowptr[wid], end = rowptr[wid + 1];
    float acc = 0.f;
    int e = beg;
    for (; e + 3 < end; e += 4) {
        uint2 e0 = cedge[e], e1 = cedge[e + 1], e2 = cedge[e + 2], e3 = cedge[e + 3];
        if (lane < NCLASS) {
            float v0 = bf2f(sup2[(size_t)e0.x * NCLASS + lane]);
            float v1 = bf2f(sup2[(size_t)e1.x * NCLASS + lane]);
            float v2 = bf2f(sup2[(size_t)e2.x * NCLASS + lane]);
            float v3 = bf2f(sup2[(size_t)e3.x * NCLASS + lane]);
            acc += __builtin_bit_cast(float, e0.y) * v0 + __builtin_bit_cast(float, e1.y) * v1 +
                   __builtin_bit_cast(float, e2.y) * v2 + __builtin_bit_cast(float, e3.y) * v3;
        }
    }
    for (; e < end; ++e) {
        uint2 e0 = cedge[e];
        if (lane < NCLASS) acc += __builtin_bit_cast(float, e0.y) * bf2f(sup2[(size_t)e0.x * NCLASS + lane]);
    }
    float v = (lane < NCLASS) ? (acc + b2[lane]) : -INFINITY;
    float m = v;
#pragma unroll
    for (int off = 32; off >= 1; off >>= 1) m = fmaxf(m, __shfl_xor(m, off));
    float ex = (lane < NCLASS) ? expf(v - m) : 0.f;
    float s = ex;
#pragma unroll
    for (int off = 32; off >= 1; off >>= 1) s += __shfl_xor(s, off);
    if (lane < NCLASS) out[(size_t)wid * NCLASS + lane] = v - m - logf(s);
}

// ---------------- launch ----------------

extern "C" void kernel_launch(void* const* d_in, const int* in_sizes, int n_in,
                              void* d_out, int out_size, void* d_ws, size_t ws_size,
                              hipStream_t stream) {
    const float* x = (const float*)d_in[0];
    const int* ei = (const int*)d_in[1];
    const float* ew = (const float*)d_in[2];
    const float* W1 = (const float*)d_in[3];
    const float* b1 = (const float*)d_in[4];
    const float* W2 = (const float*)d_in[5];
    const float* b2 = (const float*)d_in[6];
    float* out = (float*)d_out;

    int E = in_sizes[1] / 2;
    const int* src = ei;
    const int* dst = ei + E;

    char* w = (char*)d_ws;
    size_t off = 0;
    auto alloc = [&](size_t bytes) {
        void* p = w + off;
        off += (bytes + 255) & ~(size_t)255;
        return p;
    };
    unsigned short* xb = (unsigned short*)alloc((size_t)M_PAD * NFEAT * 2);   // 102.5 MB
    unsigned short* w1t = (unsigned short*)alloc((size_t)NHID * NFEAT * 2);   // 256 KB
    unsigned short* sup1 = (unsigned short*)alloc((size_t)M_PAD * NHID * 2);  // 51.2 MB
    unsigned short* h1 = (unsigned short*)alloc((size_t)N_NODES * NHID * 2);  // 51.2 MB
    uint2* cedge = (uint2*)alloc((size_t)E * 8);                              // 25.6 MB
    int* rowptr = (int*)alloc((size_t)(N_NODES + 1) * 4);
    int* deg = (int*)alloc((size_t)N_NODES * 4);
    int* bcur = (int*)alloc((size_t)NBKT * 4);
    int* bsum = (int*)alloc(2048);
    int* boff = (int*)alloc(2048);
    unsigned short* sup2 = (unsigned short*)xb;  // alias: xb dead after gemm1
    uint2* tmp = (uint2*)sup1;  // alias: sup1 first written in gemm1 (after binB)

    const int NB = (N_NODES + 255) / 256;  // 391
    const int BINA_BLOCKS = (E + BINA_CHUNK - 1) / BINA_CHUNK;

    hipMemsetAsync(deg, 0, (size_t)N_NODES * 4, stream);
    k_pre<<<HIST_BLOCKS + CVTX_BLOCKS + CVTW_BLOCKS, 256, 0, stream>>>(dst, deg, E, x, xb, W1, w1t);
    k_scan1<<<NB, 256, 0, stream>>>(deg, rowptr, bsum, N_NODES);
    k_scan2<<<1, 512, 0, stream>>>(bsum, boff, NB);
    k_scan3<<<NB, 256, 0, stream>>>(rowptr, boff, bcur, N_NODES);
    k_binA<<<BINA_BLOCKS, 256, 0, stream>>>(src, dst, ew, bcur, tmp, E);
    k_binB<<<NBKT, 256, 0, stream>>>(tmp, rowptr, cedge);

    dim3 g1(M_PAD / 128, NHID / 128);
    k_gemm1<<<g1, 256, 0, stream>>>(xb, w1t, sup1);
    k_prop1<<<(N_NODES + 3) / 4, 256, 0, stream>>>(sup1, rowptr, cedge, h1);
    k_gemm2<<<2048, 256, 0, stream>>>(h1, W2, b1, sup2);
    k_prop2<<<(N_NODES + 3) / 4, 256, 0, stream>>>(sup2, rowptr, cedge, b2, out);
}

// Round 6
// 688.859 us; speedup vs baseline: 2.1454x; 1.2217x over previous
//
#include <hip/hip_runtime.h>
#include <math.h>

#define N_NODES 100000
#define M_PAD 100096  /* 782*128 */
#define NFEAT 512
#define NHID 256
#define NCLASS 40
#define SUP2_LD 48   /* padded cols for MFMA gemm2 */

#define NBKT 250       /* coarse buckets */
#define NPB 400        /* nodes per bucket: 250*400 = 100000 exactly */
#define BINA_CHUNK 6144

typedef __attribute__((ext_vector_type(8))) short bf16x8;
typedef __attribute__((ext_vector_type(4))) float f32x4;

__device__ __forceinline__ unsigned short f2bf(float f) {
    unsigned int u = __builtin_bit_cast(unsigned int, f);
    u += 0x7fffu + ((u >> 16) & 1u);  // RNE
    return (unsigned short)(u >> 16);
}
__device__ __forceinline__ float bf2f(unsigned short u) {
    return __builtin_bit_cast(float, (unsigned int)u << 16);
}
__device__ __forceinline__ void bf2x2(unsigned int u, float& f0, float& f1) {
    f0 = __builtin_bit_cast(float, u << 16);
    f1 = __builtin_bit_cast(float, u & 0xffff0000u);
}
__device__ __forceinline__ void gload16(const void* g, void* l) {
    __builtin_amdgcn_global_load_lds(
        (const __attribute__((address_space(1))) unsigned int*)g,
        (__attribute__((address_space(3))) unsigned int*)l, 16, 0, 0);
}

// ---------------- fused pre-pass: hist + cvt_x + cvt_w1 + w2 frag-pack ----------------
#define HIST_BLOCKS 2048
#define CVTX_BLOCKS 25024 /* M_PAD*512/8/256 */
#define CVTW_BLOCKS 512   /* 256*512/256 */

__global__ __launch_bounds__(256) void k_pre(const int* __restrict__ dst, int* __restrict__ deg,
                                             int E, const float* __restrict__ x,
                                             unsigned short* __restrict__ xb,
                                             const float* __restrict__ W1,
                                             unsigned short* __restrict__ w1t,
                                             const float* __restrict__ W2,
                                             uint4* __restrict__ w2f) {
    int b = blockIdx.x;
    int t = threadIdx.x;
    if (b < HIST_BLOCKS) {
        // histogram of dst (deg pre-zeroed); vectorized int4 reads
        int tid = b * 256 + t;
        int stride4 = HIST_BLOCKS * 256 * 4;
        for (int i = tid * 4; i + 3 < E; i += stride4) {
            int4 d4 = *(const int4*)(dst + i);
            atomicAdd(&deg[d4.x], 1);
            atomicAdd(&deg[d4.y], 1);
            atomicAdd(&deg[d4.z], 1);
            atomicAdd(&deg[d4.w], 1);
        }
        if (tid == 0) {
            for (int i = E & ~3; i < E; ++i) atomicAdd(&deg[dst[i]], 1);
        }
    } else if (b < HIST_BLOCKS + CVTX_BLOCKS) {
        // x f32 -> xb bf16, pad rows zero; 8 elems/thread
        size_t i = ((size_t)(b - HIST_BLOCKS) * 256 + t) * 8;
        const size_t real = (size_t)N_NODES * NFEAT;
        unsigned short o[8];
        if (i < real) {
            float4 v0 = *(const float4*)(x + i);
            float4 v1 = *(const float4*)(x + i + 4);
            o[0]=f2bf(v0.x); o[1]=f2bf(v0.y); o[2]=f2bf(v0.z); o[3]=f2bf(v0.w);
            o[4]=f2bf(v1.x); o[5]=f2bf(v1.y); o[6]=f2bf(v1.z); o[7]=f2bf(v1.w);
        } else {
            for (int j = 0; j < 8; ++j) o[j] = 0;
        }
        *(uint4*)(xb + i) = *(const uint4*)o;
    } else if (b < HIST_BLOCKS + CVTX_BLOCKS + CVTW_BLOCKS) {
        // W1 [512][256] -> w1t [256][512] transposed bf16
        int idx = (b - HIST_BLOCKS - CVTX_BLOCKS) * 256 + t;
        int n = idx >> 9, k = idx & 511;
        w1t[idx] = f2bf(W1[(size_t)k * NHID + n]);
    } else {
        // W2 [256][40] f32 -> frag-packed bf16 w2f[ks][n][lane] (8*3*64 frags of 16B)
        for (int idx = t; idx < 8 * 3 * 64; idx += 256) {
            int ks = idx / 192;
            int rem = idx - ks * 192;
            int n = rem >> 6;
            int l = rem & 63;
            int col = n * 16 + (l & 15);
            int kbase = ks * 32 + (l >> 4) * 8;
            unsigned short o[8];
#pragma unroll
            for (int j = 0; j < 8; ++j)
                o[j] = (col < NCLASS) ? f2bf(W2[(size_t)(kbase + j) * NCLASS + col]) : 0;
            w2f[idx] = *(const uint4*)o;
        }
    }
}

// ---------------- scans ----------------

__global__ void k_scan1(const int* __restrict__ deg, int* __restrict__ rowptr,
                        int* __restrict__ bsum, int n) {
    __shared__ int sm[256];
    int t = threadIdx.x;
    int idx = blockIdx.x * 256 + t;
    int v = (idx < n) ? deg[idx] : 0;
    sm[t] = v;
    __syncthreads();
    for (int off = 1; off < 256; off <<= 1) {
        int a = (t >= off) ? sm[t - off] : 0;
        __syncthreads();
        sm[t] += a;
        __syncthreads();
    }
    if (idx < n) rowptr[idx + 1] = sm[t];
    if (t == 255) bsum[blockIdx.x] = sm[255];
    if (idx == 0) rowptr[0] = 0;
}

__global__ void k_scan2(const int* __restrict__ bsum, int* __restrict__ boff, int nb) {
    __shared__ int sm[512];
    int t = threadIdx.x;
    int v = (t < nb) ? bsum[t] : 0;
    sm[t] = v;
    __syncthreads();
    for (int off = 1; off < 512; off <<= 1) {
        int a = (t >= off) ? sm[t - off] : 0;
        __syncthreads();
        sm[t] += a;
        __syncthreads();
    }
    if (t < nb) boff[t] = sm[t] - v;
}

// finalize rowptr; init coarse-bucket cursors bcur[b] = rowptr[b*NPB]
__global__ void k_scan3(int* __restrict__ rowptr, const int* __restrict__ boff,
                        int* __restrict__ bcur, int n) {
    int idx = blockIdx.x * blockDim.x + threadIdx.x;
    if (idx < n) {
        int f = rowptr[idx + 1] + boff[idx >> 8];
        rowptr[idx + 1] = f;
        int p = idx + 1;
        if ((p % NPB) == 0 && (p / NPB) < NBKT) bcur[p / NPB] = f;
        if (idx == 0) bcur[0] = 0;
    }
}

// ---------------- binA: LDS counting-sort chunk into 250 buckets, coalesced drain ----------------
__global__ __launch_bounds__(256) void k_binA(const int* __restrict__ src,
                                              const int* __restrict__ dst,
                                              const float* __restrict__ ew,
                                              int* __restrict__ bcur,
                                              uint2* __restrict__ tmp, int E) {
    __shared__ uint2 sorted[BINA_CHUNK];        // 48 KB
    __shared__ unsigned char bkt8[BINA_CHUNK];  // 6 KB
    __shared__ int cnt[256], startv[256], offv[256], gb[256];
    int t = threadIdx.x;
    int c0 = blockIdx.x * BINA_CHUNK;
    int n = min(BINA_CHUNK, E - c0);
    cnt[t] = 0;
    __syncthreads();
    // pass 1: count
    for (int j = t; j < n; j += 256) {
        int b = (unsigned)dst[c0 + j] / NPB;
        atomicAdd(&cnt[b], 1);
    }
    __syncthreads();
    // inclusive scan of cnt (256-wide Hillis-Steele)
    int v = cnt[t];
    startv[t] = v;
    __syncthreads();
    for (int o = 1; o < 256; o <<= 1) {
        int a = (t >= o) ? startv[t - o] : 0;
        __syncthreads();
        startv[t] += a;
        __syncthreads();
    }
    int ex = startv[t] - v;  // exclusive start
    __syncthreads();
    startv[t] = ex;
    offv[t] = ex;
    if (t < NBKT) gb[t] = (v > 0) ? atomicAdd(&bcur[t], v) : 0;
    __syncthreads();
    // pass 2: rank + place into LDS (sorted by bucket)
    for (int j = t; j < n; j += 256) {
        int d = dst[c0 + j];
        int b = (unsigned)d / NPB;
        int dl = d - b * NPB;  // < 400, 9 bits
        int r = atomicAdd(&offv[b], 1);
        sorted[r] = make_uint2((unsigned)src[c0 + j] | ((unsigned)dl << 17),
                               __builtin_bit_cast(unsigned, ew[c0 + j]));
        bkt8[r] = (unsigned char)b;
    }
    __syncthreads();
    // drain: linear over sorted -> coalesced bursts per bucket region
    for (int j = t; j < n; j += 256) {
        int b = bkt8[j];
        tmp[gb[b] + (j - startv[b])] = sorted[j];
    }
}

// ---------------- binB: per-bucket fine scatter within block-private L2 window ----------------
__global__ __launch_bounds__(256) void k_binB(const uint2* __restrict__ tmp,
                                              const int* __restrict__ rowptr,
                                              uint2* __restrict__ cedge) {
    __shared__ int nc[NPB];
    int b = blockIdx.x;
    int t = threadIdx.x;
    int n0 = b * NPB;
    for (int nn = t; nn < NPB; nn += 256) nc[nn] = rowptr[n0 + nn];
    __syncthreads();
    int beg = rowptr[n0];
    int end = rowptr[n0 + NPB];
    for (int j = beg + t; j < end; j += 256) {
        uint2 e = tmp[j];
        int dl = e.x >> 17;
        int addr = atomicAdd(&nc[dl], 1);
        cedge[addr] = make_uint2(e.x & 0x1FFFFu, e.y);
    }
}

// ---------------- GEMM1 (MFMA bf16): sup1 = xb @ W1 ----------------
__global__ __launch_bounds__(256) void k_gemm1(const unsigned short* __restrict__ xb,
                                               const unsigned short* __restrict__ w1t,
                                               unsigned short* __restrict__ sup1) {
    __shared__ char smem[65536];  // A: 2x16KB @0, B: 2x16KB @32768
    const int t = threadIdx.x;
    const int w = t >> 6, lane = t & 63;
    const int m0 = blockIdx.x * 128;
    const int n0 = blockIdx.y * 128;
    const int wm = w >> 1, wn = w & 1;
    const int r15 = lane & 15, hi = lane >> 4;

    f32x4 acc[4][4];
#pragma unroll
    for (int i = 0; i < 4; ++i)
#pragma unroll
        for (int j = 0; j < 4; ++j) acc[i][j] = (f32x4){0.f, 0.f, 0.f, 0.f};

    const char* xsrc = (const char*)xb;
    const char* wsrc = (const char*)w1t;

#define STAGE(kt, b)                                                                   \
    {                                                                                  \
        char* Ab = smem + (b) * 16384;                                                 \
        char* Bb = smem + 32768 + (b) * 16384;                                         \
        _Pragma("unroll") for (int i = 0; i < 4; ++i) {                                \
            int c = i * 256 + w * 64 + lane;                                           \
            int row = c >> 3;                                                          \
            int sb = ((c & 7) * 16) ^ ((row & 7) << 4);                                \
            gload16(xsrc + ((size_t)(m0 + row) * 1024 + (kt) * 128 + sb),              \
                    Ab + (size_t)(i * 256 + w * 64) * 16);                             \
            gload16(wsrc + ((size_t)(n0 + row) * 1024 + (kt) * 128 + sb),              \
                    Bb + (size_t)(i * 256 + w * 64) * 16);                             \
        }                                                                              \
    }

    STAGE(0, 0);
    for (int kt = 0; kt < 8; ++kt) {
        __syncthreads();
        if (kt < 7) STAGE(kt + 1, (kt + 1) & 1);
        const char* Ab = smem + (kt & 1) * 16384;
        const char* Bb = smem + 32768 + (kt & 1) * 16384;
#pragma unroll
        for (int ks = 0; ks < 2; ++ks) {
            bf16x8 a[4], bb[4];
#pragma unroll
            for (int i = 0; i < 4; ++i) {
                int r = wm * 64 + i * 16 + r15;
                int cb = (ks * 64 + hi * 16) ^ ((r & 7) << 4);
                a[i] = *(const bf16x8*)(Ab + r * 128 + cb);
            }
#pragma unroll
            for (int j = 0; j < 4; ++j) {
                int n = wn * 64 + j * 16 + r15;
                int cb = (ks * 64 + hi * 16) ^ ((n & 7) << 4);
                bb[j] = *(const bf16x8*)(Bb + n * 128 + cb);
            }
#pragma unroll
            for (int i = 0; i < 4; ++i)
#pragma unroll
                for (int j = 0; j < 4; ++j)
                    acc[i][j] = __builtin_amdgcn_mfma_f32_16x16x32_bf16(a[i], bb[j], acc[i][j], 0, 0, 0);
        }
    }
#undef STAGE

#pragma unroll
    for (int i = 0; i < 4; ++i) {
        int rowb = m0 + wm * 64 + i * 16 + hi * 4;
#pragma unroll
        for (int j = 0; j < 4; ++j) {
            int col = n0 + wn * 64 + j * 16 + r15;
#pragma unroll
            for (int r = 0; r < 4; ++r)
                sup1[(size_t)(rowb + r) * NHID + col] = f2bf(acc[i][j][r]);
        }
    }
}

// ---------------- propagate 1 (bf16 rows, packed edges, 8-unroll) + bias + relu ----------------
__global__ __launch_bounds__(256) void k_prop1(const unsigned short* __restrict__ sup1,
                                               const int* __restrict__ rowptr,
                                               const uint2* __restrict__ cedge,
                                               const float* __restrict__ b1,
                                               unsigned short* __restrict__ h1) {
    int gid = blockIdx.x * blockDim.x + threadIdx.x;
    int wid = gid >> 6;
    int lane = gid & 63;
    if (wid >= N_NODES) return;
    int beg = rowptr[wid], end = rowptr[wid + 1];
    float a0 = 0.f, a1 = 0.f, a2 = 0.f, a3 = 0.f;
    int e = beg;
    for (; e + 7 < end; e += 8) {
        uint2 ed[8];
#pragma unroll
        for (int q = 0; q < 8; ++q) ed[q] = cedge[e + q];
        uint2 r[8];
#pragma unroll
        for (int q = 0; q < 8; ++q)
            r[q] = *(const uint2*)(sup1 + (size_t)ed[q].x * NHID + lane * 4);
#pragma unroll
        for (int q = 0; q < 8; ++q) {
            float wq = __builtin_bit_cast(float, ed[q].y);
            float f0, f1, f2, f3;
            bf2x2(r[q].x, f0, f1);
            bf2x2(r[q].y, f2, f3);
            a0 += wq * f0; a1 += wq * f1; a2 += wq * f2; a3 += wq * f3;
        }
    }
    for (; e < end; ++e) {
        uint2 ed = cedge[e];
        float wq = __builtin_bit_cast(float, ed.y);
        uint2 rv = *(const uint2*)(sup1 + (size_t)ed.x * NHID + lane * 4);
        float f0, f1, f2, f3;
        bf2x2(rv.x, f0, f1);
        bf2x2(rv.y, f2, f3);
        a0 += wq * f0; a1 += wq * f1; a2 += wq * f2; a3 += wq * f3;
    }
    // fused bias + relu (h1 := relu(prop + b1)), stored bf16
    float4 bv = *(const float4*)(b1 + lane * 4);
    a0 = fmaxf(a0 + bv.x, 0.f);
    a1 = fmaxf(a1 + bv.y, 0.f);
    a2 = fmaxf(a2 + bv.z, 0.f);
    a3 = fmaxf(a3 + bv.w, 0.f);
    unsigned short o[4] = {f2bf(a0), f2bf(a1), f2bf(a2), f2bf(a3)};
    *(uint2*)(h1 + (size_t)wid * NHID + lane * 4) = *(const uint2*)o;
}

// ---------------- GEMM2 (MFMA): sup2[M_PAD][48] = h1r @ W2  (W2 frag-packed) ----------------
__global__ __launch_bounds__(256) void k_gemm2(const unsigned short* __restrict__ h1,
                                               const uint4* __restrict__ w2f,
                                               unsigned short* __restrict__ sup2) {
    int t = threadIdx.x;
    int w = t >> 6, lane = t & 63;
    int m0 = (blockIdx.x * 4 + w) * 16;
    int r15 = lane & 15, hi = lane >> 4;

    bf16x8 bfrag[8][3];
#pragma unroll
    for (int ks = 0; ks < 8; ++ks)
#pragma unroll
        for (int n = 0; n < 3; ++n)
            bfrag[ks][n] = __builtin_bit_cast(bf16x8, w2f[(ks * 3 + n) * 64 + lane]);

    f32x4 acc[3];
#pragma unroll
    for (int n = 0; n < 3; ++n) acc[n] = (f32x4){0.f, 0.f, 0.f, 0.f};

    const unsigned short* arow = h1 + (size_t)(m0 + r15) * NHID + hi * 8;
#pragma unroll
    for (int ks = 0; ks < 8; ++ks) {
        bf16x8 a = *(const bf16x8*)(arow + ks * 32);
#pragma unroll
        for (int n = 0; n < 3; ++n)
            acc[n] = __builtin_amdgcn_mfma_f32_16x16x32_bf16(a, bfrag[ks][n], acc[n], 0, 0, 0);
    }
#pragma unroll
    for (int n = 0; n < 3; ++n) {
        int col = n * 16 + r15;
#pragma unroll
        for (int r = 0; r < 4; ++r) {
            int row = m0 + hi * 4 + r;
            sup2[(size_t)row * SUP2_LD + col] = f2bf(acc[n][r]);
        }
    }
}

// ---------------- propagate 2 + b2 + log_softmax (bf16 gather, stride 48) ----------------
__global__ __launch_bounds__(256) void k_prop2(const unsigned short* __restrict__ sup2,
                                               const int* __restrict__ rowptr,
                                               const uint2* __restrict__ cedge,
                                               const float* __restrict__ b2,
                                               float* __restrict__ out) {
    int gid = blockIdx.x * blockDim.x + threadIdx.x;
    int wid = gid >> 6;
    int lane = gid & 63;
    if (wid >= N_NODES) return;
    int beg = rowptr[wid], end = rowptr[wid + 1];
    float acc = 0.f;
    int e = beg;
    for (; e + 7 < end; e += 8) {
        uint2 ed[8];
#pragma unroll
        for (int q = 0; q < 8; ++q) ed[q] = cedge[e + q];
        if (lane < NCLASS) {
#pragma unroll
            for (int q = 0; q < 8; ++q) {
                float v = bf2f(sup2[(size_t)ed[q].x * SUP2_LD + lane]);
                acc += __builtin_bit_cast(float, ed[q].y) * v;
            }
        }
    }
    for (; e < end; ++e) {
        uint2 e0 = cedge[e];
        if (lane < NCLASS)
            acc += __builtin_bit_cast(float, e0.y) * bf2f(sup2[(size_t)e0.x * SUP2_LD + lane]);
    }
    float v = (lane < NCLASS) ? (acc + b2[lane]) : -INFINITY;
    float m = v;
#pragma unroll
    for (int off = 32; off >= 1; off >>= 1) m = fmaxf(m, __shfl_xor(m, off));
    float ex = (lane < NCLASS) ? expf(v - m) : 0.f;
    float s = ex;
#pragma unroll
    for (int off = 32; off >= 1; off >>= 1) s += __shfl_xor(s, off);
    if (lane < NCLASS) out[(size_t)wid * NCLASS + lane] = v - m - logf(s);
}

// ---------------- launch ----------------

extern "C" void kernel_launch(void* const* d_in, const int* in_sizes, int n_in,
                              void* d_out, int out_size, void* d_ws, size_t ws_size,
                              hipStream_t stream) {
    const float* x = (const float*)d_in[0];
    const int* ei = (const int*)d_in[1];
    const float* ew = (const float*)d_in[2];
    const float* W1 = (const float*)d_in[3];
    const float* b1 = (const float*)d_in[4];
    const float* W2 = (const float*)d_in[5];
    const float* b2 = (const float*)d_in[6];
    float* out = (float*)d_out;

    int E = in_sizes[1] / 2;
    const int* src = ei;
    const int* dst = ei + E;

    char* w = (char*)d_ws;
    size_t off = 0;
    auto alloc = [&](size_t bytes) {
        void* p = w + off;
        off += (bytes + 255) & ~(size_t)255;
        return p;
    };
    unsigned short* xb = (unsigned short*)alloc((size_t)M_PAD * NFEAT * 2);   // 102.5 MB
    unsigned short* w1t = (unsigned short*)alloc((size_t)NHID * NFEAT * 2);   // 256 KB
    unsigned short* sup1 = (unsigned short*)alloc((size_t)M_PAD * NHID * 2);  // 51.2 MB
    unsigned short* h1 = (unsigned short*)alloc((size_t)M_PAD * NHID * 2);    // 51.2 MB
    uint2* cedge = (uint2*)alloc((size_t)E * 8);                              // 25.6 MB
    int* rowptr = (int*)alloc((size_t)(N_NODES + 1) * 4);
    int* deg = (int*)alloc((size_t)N_NODES * 4);
    int* bcur = (int*)alloc((size_t)NBKT * 4);
    int* bsum = (int*)alloc(2048);
    int* boff = (int*)alloc(2048);
    uint4* w2f = (uint4*)alloc((size_t)8 * 3 * 64 * 16);  // 24 KB frag-packed W2
    unsigned short* sup2 = (unsigned short*)xb;  // alias: xb dead after gemm1 (9.6 MB <= 102.5 MB)
    uint2* tmp = (uint2*)sup1;  // alias: sup1 first written in gemm1 (after binB)

    const int NB = (N_NODES + 255) / 256;  // 391
    const int BINA_BLOCKS = (E + BINA_CHUNK - 1) / BINA_CHUNK;

    hipMemsetAsync(deg, 0, (size_t)N_NODES * 4, stream);
    k_pre<<<HIST_BLOCKS + CVTX_BLOCKS + CVTW_BLOCKS + 1, 256, 0, stream>>>(
        dst, deg, E, x, xb, W1, w1t, W2, w2f);
    k_scan1<<<NB, 256, 0, stream>>>(deg, rowptr, bsum, N_NODES);
    k_scan2<<<1, 512, 0, stream>>>(bsum, boff, NB);
    k_scan3<<<NB, 256, 0, stream>>>(rowptr, boff, bcur, N_NODES);
    k_binA<<<BINA_BLOCKS, 256, 0, stream>>>(src, dst, ew, bcur, tmp, E);
    k_binB<<<NBKT, 256, 0, stream>>>(tmp, rowptr, cedge);

    dim3 g1(M_PAD / 128, NHID / 128);
    k_gemm1<<<g1, 256, 0, stream>>>(xb, w1t, sup1);
    k_prop1<<<(N_NODES + 3) / 4, 256, 0, stream>>>(sup1, rowptr, cedge, b1, h1);
    k_gemm2<<<M_PAD / 64, 256, 0, stream>>>(h1, w2f, sup2);
    k_prop2<<<(N_NODES + 3) / 4, 256, 0, stream>>>(sup2, rowptr, cedge, b2, out);
}

// Round 7
// 657.569 us; speedup vs baseline: 2.2475x; 1.0476x over previous
//
#include <hip/hip_runtime.h>
#include <math.h>

#define N_NODES 100000
#define M_PAD 100096  /* 782*128 */
#define NFEAT 512
#define NHID 256
#define NCLASS 40
#define SUP2_LD 48   /* padded cols for MFMA gemm2 */

#define NBKT 250       /* coarse buckets */
#define NPB 400        /* nodes per bucket: 250*400 = 100000 exactly */
#define BINA_CHUNK 6144

typedef __attribute__((ext_vector_type(8))) short bf16x8;
typedef __attribute__((ext_vector_type(4))) float f32x4;

__device__ __forceinline__ unsigned short f2bf(float f) {
    unsigned int u = __builtin_bit_cast(unsigned int, f);
    u += 0x7fffu + ((u >> 16) & 1u);  // RNE
    return (unsigned short)(u >> 16);
}
__device__ __forceinline__ float bf2f(unsigned short u) {
    return __builtin_bit_cast(float, (unsigned int)u << 16);
}
__device__ __forceinline__ void bf2x2(unsigned int u, float& f0, float& f1) {
    f0 = __builtin_bit_cast(float, u << 16);
    f1 = __builtin_bit_cast(float, u & 0xffff0000u);
}
__device__ __forceinline__ void gload16(const void* g, void* l) {
    __builtin_amdgcn_global_load_lds(
        (const __attribute__((address_space(1))) unsigned int*)g,
        (__attribute__((address_space(3))) unsigned int*)l, 16, 0, 0);
}

// ---------------- fused pre-pass: hist + cvt_w1 + w2 frag-pack ----------------
#define HIST_BLOCKS 2048
#define CVTW_BLOCKS 512   /* 256*512/256 */

__global__ __launch_bounds__(256) void k_pre(const int* __restrict__ dst, int* __restrict__ deg,
                                             int E,
                                             const float* __restrict__ W1,
                                             unsigned short* __restrict__ w1t,
                                             const float* __restrict__ W2,
                                             uint4* __restrict__ w2f) {
    int b = blockIdx.x;
    int t = threadIdx.x;
    if (b < HIST_BLOCKS) {
        // histogram of dst (deg pre-zeroed); vectorized int4 reads
        int tid = b * 256 + t;
        int stride4 = HIST_BLOCKS * 256 * 4;
        for (int i = tid * 4; i + 3 < E; i += stride4) {
            int4 d4 = *(const int4*)(dst + i);
            atomicAdd(&deg[d4.x], 1);
            atomicAdd(&deg[d4.y], 1);
            atomicAdd(&deg[d4.z], 1);
            atomicAdd(&deg[d4.w], 1);
        }
        if (tid == 0) {
            for (int i = E & ~3; i < E; ++i) atomicAdd(&deg[dst[i]], 1);
        }
    } else if (b < HIST_BLOCKS + CVTW_BLOCKS) {
        // W1 [512][256] -> w1t [256][512] transposed bf16
        int idx = (b - HIST_BLOCKS) * 256 + t;
        int n = idx >> 9, k = idx & 511;
        w1t[idx] = f2bf(W1[(size_t)k * NHID + n]);
    } else {
        // W2 [256][40] f32 -> frag-packed bf16 w2f[ks][n][lane] (8*3*64 frags of 16B)
        for (int idx = t; idx < 8 * 3 * 64; idx += 256) {
            int ks = idx / 192;
            int rem = idx - ks * 192;
            int n = rem >> 6;
            int l = rem & 63;
            int col = n * 16 + (l & 15);
            int kbase = ks * 32 + (l >> 4) * 8;
            unsigned short o[8];
#pragma unroll
            for (int j = 0; j < 8; ++j)
                o[j] = (col < NCLASS) ? f2bf(W2[(size_t)(kbase + j) * NCLASS + col]) : 0;
            w2f[idx] = *(const uint4*)o;
        }
    }
}

// ---------------- scans ----------------

__global__ void k_scan1(const int* __restrict__ deg, int* __restrict__ rowptr,
                        int* __restrict__ bsum, int n) {
    __shared__ int sm[256];
    int t = threadIdx.x;
    int idx = blockIdx.x * 256 + t;
    int v = (idx < n) ? deg[idx] : 0;
    sm[t] = v;
    __syncthreads();
    for (int off = 1; off < 256; off <<= 1) {
        int a = (t >= off) ? sm[t - off] : 0;
        __syncthreads();
        sm[t] += a;
        __syncthreads();
    }
    if (idx < n) rowptr[idx + 1] = sm[t];
    if (t == 255) bsum[blockIdx.x] = sm[255];
    if (idx == 0) rowptr[0] = 0;
}

__global__ void k_scan2(const int* __restrict__ bsum, int* __restrict__ boff, int nb) {
    __shared__ int sm[512];
    int t = threadIdx.x;
    int v = (t < nb) ? bsum[t] : 0;
    sm[t] = v;
    __syncthreads();
    for (int off = 1; off < 512; off <<= 1) {
        int a = (t >= off) ? sm[t - off] : 0;
        __syncthreads();
        sm[t] += a;
        __syncthreads();
    }
    if (t < nb) boff[t] = sm[t] - v;
}

// finalize rowptr; init coarse-bucket cursors bcur[b] = rowptr[b*NPB]
__global__ void k_scan3(int* __restrict__ rowptr, const int* __restrict__ boff,
                        int* __restrict__ bcur, int n) {
    int idx = blockIdx.x * blockDim.x + threadIdx.x;
    if (idx < n) {
        int f = rowptr[idx + 1] + boff[idx >> 8];
        rowptr[idx + 1] = f;
        int p = idx + 1;
        if ((p % NPB) == 0 && (p / NPB) < NBKT) bcur[p / NPB] = f;
        if (idx == 0) bcur[0] = 0;
    }
}

// ---------------- fat kernel: binA (blocks < BINA_BLOCKS) + gemm1 (rest) ----------------
// shared union: binA needs 49152(sorted)+6144(bkt8)+4096(cnt..) = 59392 B
//               gemm1 needs A 2x8192 + B 2x16384 = 49152 B

__device__ __forceinline__ void binA_body(char* smbase, int t, int cblk,
                                          const int* __restrict__ src,
                                          const int* __restrict__ dst,
                                          const float* __restrict__ ew,
                                          int* __restrict__ bcur,
                                          uint2* __restrict__ tmp, int E) {
    uint2* sorted = (uint2*)smbase;                       // 49152
    unsigned char* bkt8 = (unsigned char*)(smbase + 49152);  // 6144
    int* cnt = (int*)(smbase + 55296);
    int* startv = cnt + 256;
    int* offv = startv + 256;
    int* gb = offv + 256;
    int c0 = cblk * BINA_CHUNK;
    int n = min(BINA_CHUNK, E - c0);
    cnt[t] = 0;
    __syncthreads();
    for (int j = t; j < n; j += 256) {
        int b = (unsigned)dst[c0 + j] / NPB;
        atomicAdd(&cnt[b], 1);
    }
    __syncthreads();
    int v = cnt[t];
    startv[t] = v;
    __syncthreads();
    for (int o = 1; o < 256; o <<= 1) {
        int a = (t >= o) ? startv[t - o] : 0;
        __syncthreads();
        startv[t] += a;
        __syncthreads();
    }
    int ex = startv[t] - v;  // exclusive start
    __syncthreads();
    startv[t] = ex;
    offv[t] = ex;
    if (t < NBKT) gb[t] = (v > 0) ? atomicAdd(&bcur[t], v) : 0;
    __syncthreads();
    for (int j = t; j < n; j += 256) {
        int d = dst[c0 + j];
        int b = (unsigned)d / NPB;
        int dl = d - b * NPB;  // < 400, 9 bits
        int r = atomicAdd(&offv[b], 1);
        sorted[r] = make_uint2((unsigned)src[c0 + j] | ((unsigned)dl << 17),
                               __builtin_bit_cast(unsigned, ew[c0 + j]));
        bkt8[r] = (unsigned char)b;
    }
    __syncthreads();
    for (int j = t; j < n; j += 256) {
        int b = bkt8[j];
        tmp[gb[b] + (j - startv[b])] = sorted[j];
    }
}

// gemm1: sup1[M_PAD][256] = bf16(x) @ W1 ; full-N 128x256 tile, BK=32
__device__ __forceinline__ void gemm1_body(char* smem, int t, int mb,
                                           const float* __restrict__ x,
                                           const unsigned short* __restrict__ w1t,
                                           unsigned short* __restrict__ sup1) {
    const int w = t >> 6, lane = t & 63;
    const int m0 = mb * 128;
    const int wm = w >> 1, wn = w & 1;
    const int r15 = lane & 15, hi = lane >> 4;

    f32x4 acc[4][8];
#pragma unroll
    for (int i = 0; i < 4; ++i)
#pragma unroll
        for (int j = 0; j < 8; ++j) acc[i][j] = (f32x4){0.f, 0.f, 0.f, 0.f};

    const char* wsrc = (const char*)w1t;

#define STAGE1(kt, b)                                                                  \
    {                                                                                  \
        char* Ab = smem + (b) * 8192;                                                  \
        char* Bb = smem + 16384 + (b) * 16384;                                         \
        _Pragma("unroll") for (int i = 0; i < 2; ++i) {                                \
            int u = i * 256 + t;                                                       \
            int row = u >> 2, part = u & 3;                                            \
            int gr = m0 + row;                                                         \
            unsigned short ob[8];                                                      \
            if (gr < N_NODES) {                                                        \
                const float* sp = x + (size_t)gr * NFEAT + (kt) * 32 + part * 8;       \
                float4 v0 = *(const float4*)sp;                                        \
                float4 v1 = *(const float4*)(sp + 4);                                  \
                ob[0] = f2bf(v0.x); ob[1] = f2bf(v0.y);                                \
                ob[2] = f2bf(v0.z); ob[3] = f2bf(v0.w);                                \
                ob[4] = f2bf(v1.x); ob[5] = f2bf(v1.y);                                \
                ob[6] = f2bf(v1.z); ob[7] = f2bf(v1.w);                                \
            } else {                                                                   \
                _Pragma("unroll") for (int j = 0; j < 8; ++j) ob[j] = 0;               \
            }                                                                          \
            *(uint4*)(Ab + row * 64 + ((part ^ ((row >> 1) & 3)) << 4)) =              \
                *(const uint4*)ob;                                                     \
        }                                                                              \
        _Pragma("unroll") for (int i = 0; i < 4; ++i) {                                \
            int u = i * 256 + t;                                                       \
            int nrow = u >> 2, part = u & 3;                                           \
            int q = part ^ ((nrow >> 1) & 3);                                          \
            gload16(wsrc + (size_t)nrow * 1024 + (kt) * 64 + q * 16, Bb + u * 16);     \
        }                                                                              \
    }

    STAGE1(0, 0);
    for (int kt = 0; kt < 16; ++kt) {
        __syncthreads();
        if (kt < 15) STAGE1(kt + 1, (kt + 1) & 1);
        const char* Ab = smem + (kt & 1) * 8192;
        const char* Bb = smem + 16384 + (kt & 1) * 16384;
        bf16x8 a[4], bb[8];
#pragma unroll
        for (int i = 0; i < 4; ++i) {
            int r = wm * 64 + i * 16 + r15;
            a[i] = *(const bf16x8*)(Ab + r * 64 + ((hi ^ ((r >> 1) & 3)) << 4));
        }
#pragma unroll
        for (int j = 0; j < 8; ++j) {
            int n = wn * 128 + j * 16 + r15;
            bb[j] = *(const bf16x8*)(Bb + n * 64 + ((hi ^ ((n >> 1) & 3)) << 4));
        }
#pragma unroll
        for (int i = 0; i < 4; ++i)
#pragma unroll
            for (int j = 0; j < 8; ++j)
                acc[i][j] = __builtin_amdgcn_mfma_f32_16x16x32_bf16(a[i], bb[j], acc[i][j], 0, 0, 0);
    }
#undef STAGE1

#pragma unroll
    for (int i = 0; i < 4; ++i) {
        int rowb = m0 + wm * 64 + i * 16 + hi * 4;
#pragma unroll
        for (int j = 0; j < 8; ++j) {
            int col = wn * 128 + j * 16 + r15;
#pragma unroll
            for (int r = 0; r < 4; ++r)
                sup1[(size_t)(rowb + r) * NHID + col] = f2bf(acc[i][j][r]);
        }
    }
}

__global__ __launch_bounds__(256) void k_fat(const int* __restrict__ src,
                                             const int* __restrict__ dst,
                                             const float* __restrict__ ew,
                                             int* __restrict__ bcur,
                                             uint2* __restrict__ tmp, int E, int binaBlocks,
                                             const float* __restrict__ x,
                                             const unsigned short* __restrict__ w1t,
                                             unsigned short* __restrict__ sup1) {
    __shared__ __align__(16) char smem[59392];
    int b = blockIdx.x;
    int t = threadIdx.x;
    if (b < binaBlocks) {
        binA_body(smem, t, b, src, dst, ew, bcur, tmp, E);
    } else {
        gemm1_body(smem, t, b - binaBlocks, x, w1t, sup1);
    }
}

// ---------------- binB: per-bucket fine scatter within block-private L2 window ----------------
__global__ __launch_bounds__(256) void k_binB(const uint2* __restrict__ tmp,
                                              const int* __restrict__ rowptr,
                                              uint2* __restrict__ cedge) {
    __shared__ int nc[NPB];
    int b = blockIdx.x;
    int t = threadIdx.x;
    int n0 = b * NPB;
    for (int nn = t; nn < NPB; nn += 256) nc[nn] = rowptr[n0 + nn];
    __syncthreads();
    int beg = rowptr[n0];
    int end = rowptr[n0 + NPB];
    for (int j = beg + t; j < end; j += 256) {
        uint2 e = tmp[j];
        int dl = e.x >> 17;
        int addr = atomicAdd(&nc[dl], 1);
        cedge[addr] = make_uint2(e.x & 0x1FFFFu, e.y);
    }
}

// ---------------- propagate 1 (bf16 rows, packed edges, 8-unroll) + bias + relu ----------------
__global__ __launch_bounds__(256) void k_prop1(const unsigned short* __restrict__ sup1,
                                               const int* __restrict__ rowptr,
                                               const uint2* __restrict__ cedge,
                                               const float* __restrict__ b1,
                                               unsigned short* __restrict__ h1) {
    int gid = blockIdx.x * blockDim.x + threadIdx.x;
    int wid = gid >> 6;
    int lane = gid & 63;
    if (wid >= N_NODES) return;
    int beg = rowptr[wid], end = rowptr[wid + 1];
    float a0 = 0.f, a1 = 0.f, a2 = 0.f, a3 = 0.f;
    int e = beg;
    for (; e + 7 < end; e += 8) {
        uint2 ed[8];
#pragma unroll
        for (int q = 0; q < 8; ++q) ed[q] = cedge[e + q];
        uint2 r[8];
#pragma unroll
        for (int q = 0; q < 8; ++q)
            r[q] = *(const uint2*)(sup1 + (size_t)ed[q].x * NHID + lane * 4);
#pragma unroll
        for (int q = 0; q < 8; ++q) {
            float wq = __builtin_bit_cast(float, ed[q].y);
            float f0, f1, f2, f3;
            bf2x2(r[q].x, f0, f1);
            bf2x2(r[q].y, f2, f3);
            a0 += wq * f0; a1 += wq * f1; a2 += wq * f2; a3 += wq * f3;
        }
    }
    for (; e < end; ++e) {
        uint2 ed = cedge[e];
        float wq = __builtin_bit_cast(float, ed.y);
        uint2 rv = *(const uint2*)(sup1 + (size_t)ed.x * NHID + lane * 4);
        float f0, f1, f2, f3;
        bf2x2(rv.x, f0, f1);
        bf2x2(rv.y, f2, f3);
        a0 += wq * f0; a1 += wq * f1; a2 += wq * f2; a3 += wq * f3;
    }
    // fused bias + relu (h1 := relu(prop + b1)), stored bf16
    float4 bv = *(const float4*)(b1 + lane * 4);
    a0 = fmaxf(a0 + bv.x, 0.f);
    a1 = fmaxf(a1 + bv.y, 0.f);
    a2 = fmaxf(a2 + bv.z, 0.f);
    a3 = fmaxf(a3 + bv.w, 0.f);
    unsigned short o[4] = {f2bf(a0), f2bf(a1), f2bf(a2), f2bf(a3)};
    *(uint2*)(h1 + (size_t)wid * NHID + lane * 4) = *(const uint2*)o;
}

// ---------------- GEMM2 (MFMA): sup2[M_PAD][48] = h1 @ W2  (W2 frag-packed) ----------------
__global__ __launch_bounds__(256) void k_gemm2(const unsigned short* __restrict__ h1,
                                               const uint4* __restrict__ w2f,
                                               unsigned short* __restrict__ sup2) {
    int t = threadIdx.x;
    int w = t >> 6, lane = t & 63;
    int m0 = (blockIdx.x * 4 + w) * 16;
    int r15 = lane & 15, hi = lane >> 4;

    bf16x8 bfrag[8][3];
#pragma unroll
    for (int ks = 0; ks < 8; ++ks)
#pragma unroll
        for (int n = 0; n < 3; ++n)
            bfrag[ks][n] = __builtin_bit_cast(bf16x8, w2f[(ks * 3 + n) * 64 + lane]);

    f32x4 acc[3];
#pragma unroll
    for (int n = 0; n < 3; ++n) acc[n] = (f32x4){0.f, 0.f, 0.f, 0.f};

    const unsigned short* arow = h1 + (size_t)(m0 + r15) * NHID + hi * 8;
#pragma unroll
    for (int ks = 0; ks < 8; ++ks) {
        bf16x8 a = *(const bf16x8*)(arow + ks * 32);
#pragma unroll
        for (int n = 0; n < 3; ++n)
            acc[n] = __builtin_amdgcn_mfma_f32_16x16x32_bf16(a, bfrag[ks][n], acc[n], 0, 0, 0);
    }
#pragma unroll
    for (int n = 0; n < 3; ++n) {
        int col = n * 16 + r15;
#pragma unroll
        for (int r = 0; r < 4; ++r) {
            int row = m0 + hi * 4 + r;
            sup2[(size_t)row * SUP2_LD + col] = f2bf(acc[n][r]);
        }
    }
}

// ---------------- propagate 2 + b2 + log_softmax (bf16 gather, stride 48) ----------------
__global__ __launch_bounds__(256) void k_prop2(const unsigned short* __restrict__ sup2,
                                               const int* __restrict__ rowptr,
                                               const uint2* __restrict__ cedge,
                                               const float* __restrict__ b2,
                                               float* __restrict__ out) {
    int gid = blockIdx.x * blockDim.x + threadIdx.x;
    int wid = gid >> 6;
    int lane = gid & 63;
    if (wid >= N_NODES) return;
    int beg = rowptr[wid], end = rowptr[wid + 1];
    float acc = 0.f;
    int e = beg;
    for (; e + 7 < end; e += 8) {
        uint2 ed[8];
#pragma unroll
        for (int q = 0; q < 8; ++q) ed[q] = cedge[e + q];
        if (lane < NCLASS) {
#pragma unroll
            for (int q = 0; q < 8; ++q) {
                float v = bf2f(sup2[(size_t)ed[q].x * SUP2_LD + lane]);
                acc += __builtin_bit_cast(float, ed[q].y) * v;
            }
        }
    }
    for (; e < end; ++e) {
        uint2 e0 = cedge[e];
        if (lane < NCLASS)
            acc += __builtin_bit_cast(float, e0.y) * bf2f(sup2[(size_t)e0.x * SUP2_LD + lane]);
    }
    float v = (lane < NCLASS) ? (acc + b2[lane]) : -INFINITY;
    float m = v;
#pragma unroll
    for (int off = 32; off >= 1; off >>= 1) m = fmaxf(m, __shfl_xor(m, off));
    float ex = (lane < NCLASS) ? expf(v - m) : 0.f;
    float s = ex;
#pragma unroll
    for (int off = 32; off >= 1; off >>= 1) s += __shfl_xor(s, off);
    if (lane < NCLASS) out[(size_t)wid * NCLASS + lane] = v - m - logf(s);
}

// ---------------- launch ----------------

extern "C" void kernel_launch(void* const* d_in, const int* in_sizes, int n_in,
                              void* d_out, int out_size, void* d_ws, size_t ws_size,
                              hipStream_t stream) {
    const float* x = (const float*)d_in[0];
    const int* ei = (const int*)d_in[1];
    const float* ew = (const float*)d_in[2];
    const float* W1 = (const float*)d_in[3];
    const float* b1 = (const float*)d_in[4];
    const float* W2 = (const float*)d_in[5];
    const float* b2 = (const float*)d_in[6];
    float* out = (float*)d_out;

    int E = in_sizes[1] / 2;
    const int* src = ei;
    const int* dst = ei + E;

    char* w = (char*)d_ws;
    size_t off = 0;
    auto alloc = [&](size_t bytes) {
        void* p = w + off;
        off += (bytes + 255) & ~(size_t)255;
        return p;
    };
    unsigned short* w1t = (unsigned short*)alloc((size_t)NHID * NFEAT * 2);   // 256 KB
    unsigned short* sup1 = (unsigned short*)alloc((size_t)M_PAD * NHID * 2);  // 51.2 MB
    unsigned short* h1 = (unsigned short*)alloc((size_t)M_PAD * NHID * 2);    // 51.2 MB
    uint2* cedge = (uint2*)alloc((size_t)E * 8);                              // 25.6 MB
    uint2* tmp = (uint2*)alloc((size_t)E * 8);                                // 25.6 MB (separate: co-runs with gemm1)
    unsigned short* sup2 = (unsigned short*)alloc((size_t)M_PAD * SUP2_LD * 2); // 9.6 MB
    int* rowptr = (int*)alloc((size_t)(N_NODES + 1) * 4);
    int* deg = (int*)alloc((size_t)N_NODES * 4);
    int* bcur = (int*)alloc((size_t)NBKT * 4);
    int* bsum = (int*)alloc(2048);
    int* boff = (int*)alloc(2048);
    uint4* w2f = (uint4*)alloc((size_t)8 * 3 * 64 * 16);  // 24 KB frag-packed W2

    const int NB = (N_NODES + 255) / 256;  // 391
    const int BINA_BLOCKS = (E + BINA_CHUNK - 1) / BINA_CHUNK;

    hipMemsetAsync(deg, 0, (size_t)N_NODES * 4, stream);
    k_pre<<<HIST_BLOCKS + CVTW_BLOCKS + 1, 256, 0, stream>>>(dst, deg, E, W1, w1t, W2, w2f);
    k_scan1<<<NB, 256, 0, stream>>>(deg, rowptr, bsum, N_NODES);
    k_scan2<<<1, 512, 0, stream>>>(bsum, boff, NB);
    k_scan3<<<NB, 256, 0, stream>>>(rowptr, boff, bcur, N_NODES);
    k_fat<<<BINA_BLOCKS + M_PAD / 128, 256, 0, stream>>>(src, dst, ew, bcur, tmp, E,
                                                          BINA_BLOCKS, x, w1t, sup1);
    k_binB<<<NBKT, 256, 0, stream>>>(tmp, rowptr, cedge);
    k_prop1<<<(N_NODES + 3) / 4, 256, 0, stream>>>(sup1, rowptr, cedge, b1, h1);
    k_gemm2<<<M_PAD / 64, 256, 0, stream>>>(h1, w2f, sup2);
    k_prop2<<<(N_NODES + 3) / 4, 256, 0, stream>>>(sup2, rowptr, cedge, b2, out);
}